// Round 1
// baseline (1591.726 us; speedup 1.0000x reference)
//
#include <hip/hip_runtime.h>

#define DD 128

typedef __attribute__((ext_vector_type(8))) short short8;
typedef __attribute__((ext_vector_type(4))) float f32x4;

__device__ inline unsigned short f2bf(float f) {
    unsigned u = __float_as_uint(f);
    unsigned r = u + 0x7fffu + ((u >> 16) & 1u);
    return (unsigned short)(r >> 16);
}
__device__ inline float bf2f(unsigned short s) {
    return __uint_as_float(((unsigned)s) << 16);
}

// ---------------- Kernel 1: BN stats (sum, sumsq per feature) ----------------
__global__ __launch_bounds__(256) void bn_stats_k(
    const float4* __restrict__ x, float* __restrict__ stats, int n) {
    int tid = threadIdx.x;
    int c4 = tid & 31;      // which float4 column (0..31)
    int sub = tid >> 5;     // row-substream within block (0..7)
    float sx = 0.f, sy = 0.f, sz = 0.f, sw = 0.f;
    float qx = 0.f, qy = 0.f, qz = 0.f, qw = 0.f;
    for (int r = blockIdx.x * 8 + sub; r < n; r += gridDim.x * 8) {
        float4 v = x[(size_t)r * 32 + c4];
        sx += v.x; sy += v.y; sz += v.z; sw += v.w;
        qx += v.x * v.x; qy += v.y * v.y; qz += v.z * v.z; qw += v.w * v.w;
    }
    __shared__ float ls[8][256];
    ls[sub][c4 * 4 + 0] = sx; ls[sub][c4 * 4 + 1] = sy;
    ls[sub][c4 * 4 + 2] = sz; ls[sub][c4 * 4 + 3] = sw;
    ls[sub][128 + c4 * 4 + 0] = qx; ls[sub][128 + c4 * 4 + 1] = qy;
    ls[sub][128 + c4 * 4 + 2] = qz; ls[sub][128 + c4 * 4 + 3] = qw;
    __syncthreads();
    float t = 0.f;
#pragma unroll
    for (int k = 0; k < 8; ++k) t += ls[k][tid];
    atomicAdd(&stats[tid], t);
}

// ---------------- Kernel 2: normalize -> h (bf16) ----------------
__global__ __launch_bounds__(256) void normalize_k(
    const float4* __restrict__ x, const float* __restrict__ stats,
    const float4* __restrict__ gamma, const float4* __restrict__ beta,
    uint2* __restrict__ hbuf, int n, float inv_n) {
    int tid = threadIdx.x;
    int c4 = tid & 31, sub = tid >> 5;
    int row = blockIdx.x * 8 + sub;
    if (row >= n) return;
    const float4* s4 = (const float4*)stats;
    float4 sm = s4[c4], sq = s4[32 + c4];
    float4 g = gamma[c4], bt = beta[c4];
    float mx = sm.x * inv_n, my = sm.y * inv_n, mz = sm.z * inv_n, mw = sm.w * inv_n;
    float vx = sq.x * inv_n - mx * mx, vy = sq.y * inv_n - my * my;
    float vz = sq.z * inv_n - mz * mz, vw = sq.w * inv_n - mw * mw;
    float scx = rsqrtf(vx + 1e-5f) * g.x, scy = rsqrtf(vy + 1e-5f) * g.y;
    float scz = rsqrtf(vz + 1e-5f) * g.z, scw = rsqrtf(vw + 1e-5f) * g.w;
    float shx = bt.x - mx * scx, shy = bt.y - my * scy;
    float shz = bt.z - mz * scz, shw = bt.w - mw * scw;
    float4 v = x[(size_t)row * 32 + c4];
    float hx = v.x * scx + shx, hy = v.y * scy + shy;
    float hz = v.z * scz + shz, hw = v.w * scw + shw;
    uint2 o;
    o.x = (unsigned)f2bf(hx) | ((unsigned)f2bf(hy) << 16);
    o.y = (unsigned)f2bf(hz) | ((unsigned)f2bf(hw) << 16);
    hbuf[(size_t)row * 32 + c4] = o;
}

// ---------------- Kernel 3: degree count ----------------
__global__ __launch_bounds__(256) void deg_k(
    const int* __restrict__ dst, float* __restrict__ deg, int nE) {
    int e = blockIdx.x * 256 + threadIdx.x;
    if (e < nE) atomicAdd(&deg[dst[e]], 1.0f);
}

// ---------------- Kernel 4: edge gather + scatter-add (fp32 atomics) --------
__global__ __launch_bounds__(256) void scatter_k(
    const int* __restrict__ src, const int* __restrict__ dst,
    const uint2* __restrict__ h, float* agg, int nE) {
    int gid = blockIdx.x * 256 + threadIdx.x;
    int e = gid >> 5;
    if (e >= nE) return;
    int c4 = gid & 31;
    int si = src[e], di = dst[e];
    uint2 u = h[(size_t)si * 32 + c4];
    float* a = agg + (size_t)di * 128 + c4 * 4;
    atomicAdd(a + 0, bf2f((unsigned short)(u.x & 0xffff)));
    atomicAdd(a + 1, bf2f((unsigned short)(u.x >> 16)));
    atomicAdd(a + 2, bf2f((unsigned short)(u.y & 0xffff)));
    atomicAdd(a + 3, bf2f((unsigned short)(u.y >> 16)));
}

// ---------------- Kernel 5: fused GEMM (K=256) + bias + skip + GELU ---------
// C[row][col] = gelu( h@Wself + (agg/deg)@Wneigh + b + h )
// B = [Wself; Wneigh] staged into LDS in MFMA-fragment order (bf16).
__global__ __launch_bounds__(256) void gemm_k(
    const unsigned short* __restrict__ h, const float* agg,
    const float* __restrict__ deg, const float* __restrict__ Wself,
    const float* __restrict__ Wneigh, const float* __restrict__ bias,
    float* out, int n) {
    __shared__ unsigned short Bsw[32768];  // 64 KB: [k_step(8)][n_tile(8)][lane(64)][8 bf16]
    int tid = threadIdx.x;
    // ---- stage B (whole 256x128), pre-swizzled into fragment order ----
#pragma unroll
    for (int i = 0; i < 16; ++i) {
        int q = tid + i * 256;              // 0..4095 slots
        int l = q & 63;
        int kb = ((q >> 9) << 5) + ((l >> 4) << 3);   // k base of this slot
        int nn = (((q >> 6) & 7) << 4) + (l & 15);    // output column
        const float* Wp = (kb < 128) ? (Wself + (size_t)kb * 128 + nn)
                                     : (Wneigh + (size_t)(kb - 128) * 128 + nn);
        unsigned tmp[4];
#pragma unroll
        for (int j = 0; j < 4; ++j) {
            float v0 = Wp[(2 * j) * 128];
            float v1 = Wp[(2 * j + 1) * 128];
            tmp[j] = (unsigned)f2bf(v0) | ((unsigned)f2bf(v1) << 16);
        }
        uint4 w; w.x = tmp[0]; w.y = tmp[1]; w.z = tmp[2]; w.w = tmp[3];
        *(uint4*)&Bsw[q * 8] = w;
    }
    __syncthreads();

    int wave = tid >> 6, lane = tid & 63;
    int quad = lane >> 4, mrow = lane & 15;
    int r0 = blockIdx.x * 128 + wave * 32;
    int rA0 = min(r0 + mrow, n - 1);
    int rA1 = min(r0 + 16 + mrow, n - 1);
    float rd0 = 1.0f / fmaxf(deg[rA0], 1.0f);
    float rd1 = 1.0f / fmaxf(deg[rA1], 1.0f);

    f32x4 zero = {0.0f, 0.0f, 0.0f, 0.0f};
    f32x4 acc[2][8];
#pragma unroll
    for (int a = 0; a < 2; ++a)
#pragma unroll
        for (int t = 0; t < 8; ++t) acc[a][t] = zero;

#pragma unroll
    for (int s = 0; s < 8; ++s) {
        int kb = s * 32 + quad * 8;
        short8 a0, a1;
        if (s < 4) {
            a0 = *(const short8*)(h + (size_t)rA0 * 128 + kb);
            a1 = *(const short8*)(h + (size_t)rA1 * 128 + kb);
        } else {
            int kk = kb - 128;
            const f32x4* p0 = (const f32x4*)(agg + (size_t)rA0 * 128 + kk);
            const f32x4* p1 = (const f32x4*)(agg + (size_t)rA1 * 128 + kk);
            f32x4 u00 = p0[0], u01 = p0[1];
            f32x4 u10 = p1[0], u11 = p1[1];
#pragma unroll
            for (int j = 0; j < 4; ++j) {
                a0[j]     = (short)f2bf(u00[j] * rd0);
                a0[j + 4] = (short)f2bf(u01[j] * rd0);
                a1[j]     = (short)f2bf(u10[j] * rd1);
                a1[j + 4] = (short)f2bf(u11[j] * rd1);
            }
        }
#pragma unroll
        for (int t = 0; t < 8; ++t) {
            short8 b = *(const short8*)(Bsw + ((size_t)(s * 8 + t) * 64 + lane) * 8);
            acc[0][t] = __builtin_amdgcn_mfma_f32_16x16x32_bf16(a0, b, acc[0][t], 0, 0, 0);
            acc[1][t] = __builtin_amdgcn_mfma_f32_16x16x32_bf16(a1, b, acc[1][t], 0, 0, 0);
        }
    }

    // ---- epilogue: bias + skip + exact GELU ----
    float bi[8];
#pragma unroll
    for (int t = 0; t < 8; ++t) bi[t] = bias[t * 16 + mrow];
#pragma unroll
    for (int tm = 0; tm < 2; ++tm) {
#pragma unroll
        for (int i = 0; i < 4; ++i) {
            int row = r0 + tm * 16 + quad * 4 + i;
            if (row < n) {
#pragma unroll
                for (int t = 0; t < 8; ++t) {
                    int col = t * 16 + mrow;
                    float xv = acc[tm][t][i] + bi[t] + bf2f(h[(size_t)row * 128 + col]);
                    float g = 0.5f * xv * (1.0f + erff(xv * 0.70710678f));
                    out[(size_t)row * 128 + col] = g;
                }
            }
        }
    }
}

extern "C" void kernel_launch(void* const* d_in, const int* in_sizes, int n_in,
                              void* d_out, int out_size, void* d_ws, size_t ws_size,
                              hipStream_t stream) {
    const float* features = (const float*)d_in[0];
    const int* src = (const int*)d_in[1];
    const int* dst = (const int*)d_in[2];
    const float* gamma = (const float*)d_in[3];
    const float* beta = (const float*)d_in[4];
    const float* Wself = (const float*)d_in[5];
    const float* Wneigh = (const float*)d_in[6];
    const float* bias = (const float*)d_in[7];
    int n = in_sizes[0] / DD;
    int nE = in_sizes[1];

    char* ws = (char*)d_ws;
    float* stats = (float*)ws;                                   // 256 floats
    float* deg = (float*)(ws + 1024);                            // n floats
    size_t deg_bytes = ((size_t)n * 4 + 1023) & ~(size_t)1023;
    unsigned short* hbuf = (unsigned short*)(ws + 1024 + deg_bytes); // n*128 bf16
    float* agg = (float*)d_out;  // reuse output buffer as the fp32 aggregator

    hipMemsetAsync(stats, 0, 1024, stream);
    hipMemsetAsync(deg, 0, (size_t)n * 4, stream);
    hipMemsetAsync(d_out, 0, (size_t)out_size * 4, stream);

    bn_stats_k<<<1024, 256, 0, stream>>>((const float4*)features, stats, n);
    normalize_k<<<(n + 7) / 8, 256, 0, stream>>>(
        (const float4*)features, stats, (const float4*)gamma,
        (const float4*)beta, (uint2*)hbuf, n, 1.0f / (float)n);
    deg_k<<<(nE + 255) / 256, 256, 0, stream>>>(dst, deg, nE);
    scatter_k<<<(nE * 32 + 255) / 256, 256, 0, stream>>>(src, dst,
        (const uint2*)hbuf, agg, nE);
    gemm_k<<<(n + 127) / 128, 256, 0, stream>>>(hbuf, agg, deg, Wself, Wneigh,
        bias, (float*)d_out, n);
}

// Round 2
// 572.207 us; speedup vs baseline: 2.7817x; 2.7817x over previous
//
#include <hip/hip_runtime.h>

#define DD 128

typedef __attribute__((ext_vector_type(8))) short short8;
typedef __attribute__((ext_vector_type(4))) float f32x4;

__device__ inline unsigned short f2bf(float f) {
    unsigned u = __float_as_uint(f);
    unsigned r = u + 0x7fffu + ((u >> 16) & 1u);
    return (unsigned short)(r >> 16);
}
__device__ inline float bf2f(unsigned short s) {
    return __uint_as_float(((unsigned)s) << 16);
}

// ---------------- Kernel 1: BN stats (sum, sumsq per feature) ----------------
__global__ __launch_bounds__(256) void bn_stats_k(
    const float4* __restrict__ x, float* __restrict__ stats, int n) {
    int tid = threadIdx.x;
    int c4 = tid & 31;      // which float4 column (0..31)
    int sub = tid >> 5;     // row-substream within block (0..7)
    float sx = 0.f, sy = 0.f, sz = 0.f, sw = 0.f;
    float qx = 0.f, qy = 0.f, qz = 0.f, qw = 0.f;
    for (int r = blockIdx.x * 8 + sub; r < n; r += gridDim.x * 8) {
        float4 v = x[(size_t)r * 32 + c4];
        sx += v.x; sy += v.y; sz += v.z; sw += v.w;
        qx += v.x * v.x; qy += v.y * v.y; qz += v.z * v.z; qw += v.w * v.w;
    }
    __shared__ float ls[8][256];
    ls[sub][c4 * 4 + 0] = sx; ls[sub][c4 * 4 + 1] = sy;
    ls[sub][c4 * 4 + 2] = sz; ls[sub][c4 * 4 + 3] = sw;
    ls[sub][128 + c4 * 4 + 0] = qx; ls[sub][128 + c4 * 4 + 1] = qy;
    ls[sub][128 + c4 * 4 + 2] = qz; ls[sub][128 + c4 * 4 + 3] = qw;
    __syncthreads();
    float t = 0.f;
#pragma unroll
    for (int k = 0; k < 8; ++k) t += ls[k][tid];
    atomicAdd(&stats[tid], t);
}

// ---------------- Kernel 2: normalize -> h (bf16) ----------------
__global__ __launch_bounds__(256) void normalize_k(
    const float4* __restrict__ x, const float* __restrict__ stats,
    const float4* __restrict__ gamma, const float4* __restrict__ beta,
    uint2* __restrict__ hbuf, int n, float inv_n) {
    int tid = threadIdx.x;
    int c4 = tid & 31, sub = tid >> 5;
    int row = blockIdx.x * 8 + sub;
    if (row >= n) return;
    const float4* s4 = (const float4*)stats;
    float4 sm = s4[c4], sq = s4[32 + c4];
    float4 g = gamma[c4], bt = beta[c4];
    float mx = sm.x * inv_n, my = sm.y * inv_n, mz = sm.z * inv_n, mw = sm.w * inv_n;
    float vx = sq.x * inv_n - mx * mx, vy = sq.y * inv_n - my * my;
    float vz = sq.z * inv_n - mz * mz, vw = sq.w * inv_n - mw * mw;
    float scx = rsqrtf(vx + 1e-5f) * g.x, scy = rsqrtf(vy + 1e-5f) * g.y;
    float scz = rsqrtf(vz + 1e-5f) * g.z, scw = rsqrtf(vw + 1e-5f) * g.w;
    float shx = bt.x - mx * scx, shy = bt.y - my * scy;
    float shz = bt.z - mz * scz, shw = bt.w - mw * scw;
    float4 v = x[(size_t)row * 32 + c4];
    float hx = v.x * scx + shx, hy = v.y * scy + shy;
    float hz = v.z * scz + shz, hw = v.w * scw + shw;
    uint2 o;
    o.x = (unsigned)f2bf(hx) | ((unsigned)f2bf(hy) << 16);
    o.y = (unsigned)f2bf(hz) | ((unsigned)f2bf(hw) << 16);
    hbuf[(size_t)row * 32 + c4] = o;
}

// ---------------- Kernel 3: degree histogram (int atomics) ----------------
__global__ __launch_bounds__(256) void hist_k(
    const int* __restrict__ dst, int* __restrict__ deg, int nE) {
    int e = blockIdx.x * 256 + threadIdx.x;
    if (e < nE) atomicAdd(&deg[dst[e]], 1);
}

// ---------------- Kernel 4: single-block exclusive scan -> CSR offsets ------
__global__ __launch_bounds__(1024) void scan_k(
    const int* __restrict__ deg, int* __restrict__ offsets,
    int* __restrict__ cursor, int n) {
    __shared__ int ps[1024];
    int t = threadIdx.x;
    int C = (n + 1023) >> 10;
    int lo = t * C, hi = min(lo + C, n);
    int s = 0;
    for (int i = lo; i < hi; ++i) s += deg[i];
    ps[t] = s;
    __syncthreads();
    for (int off = 1; off < 1024; off <<= 1) {
        int v = (t >= off) ? ps[t - off] : 0;
        __syncthreads();
        ps[t] += v;
        __syncthreads();
    }
    int run = (t == 0) ? 0 : ps[t - 1];
    for (int i = lo; i < hi; ++i) {
        offsets[i] = run; cursor[i] = run;
        run += deg[i];
    }
    if (t == 1023) offsets[n] = run;
}

// ---------------- Kernel 5: bin src indices into CSR ----------------
__global__ __launch_bounds__(256) void bin_k(
    const int* __restrict__ src, const int* __restrict__ dst,
    int* __restrict__ cursor, int* __restrict__ csr, int nE) {
    int e = blockIdx.x * 256 + threadIdx.x;
    if (e < nE) {
        int p = atomicAdd(&cursor[dst[e]], 1);
        csr[p] = src[e];
    }
}

// ---------------- Kernel 6: pull aggregation (no atomics) ----------------
// One wave per dst node; lane l holds features 2l, 2l+1. Writes h_neigh fp32
// (already divided by deg) into d_out (reused; gemm block reads its own rows).
__global__ __launch_bounds__(256) void pull_k(
    const int* __restrict__ offsets, const int* __restrict__ csr,
    const unsigned* __restrict__ h32, float* __restrict__ hn, int n) {
    int wid = (blockIdx.x * 256 + threadIdx.x) >> 6;
    int lane = threadIdx.x & 63;
    if (wid >= n) return;
    int b0 = offsets[wid], b1 = offsets[wid + 1];
    float a0 = 0.f, a1 = 0.f;
    int j = b0;
    for (; j + 2 <= b1; j += 2) {
        int s0 = csr[j], s1 = csr[j + 1];
        unsigned u0 = h32[(size_t)s0 * 64 + lane];
        unsigned u1 = h32[(size_t)s1 * 64 + lane];
        a0 += bf2f((unsigned short)(u0 & 0xffff)) + bf2f((unsigned short)(u1 & 0xffff));
        a1 += bf2f((unsigned short)(u0 >> 16)) + bf2f((unsigned short)(u1 >> 16));
    }
    if (j < b1) {
        int s0 = csr[j];
        unsigned u0 = h32[(size_t)s0 * 64 + lane];
        a0 += bf2f((unsigned short)(u0 & 0xffff));
        a1 += bf2f((unsigned short)(u0 >> 16));
    }
    float rd = (b1 > b0) ? 1.0f / (float)(b1 - b0) : 0.0f;
    float2 o; o.x = a0 * rd; o.y = a1 * rd;
    *(float2*)(hn + (size_t)wid * 128 + lane * 2) = o;
}

// ---------------- Kernel 7: fused GEMM (K=256) + bias + skip + GELU ---------
// C[row][col] = gelu( h@Wself + hn@Wneigh + b + h )
__global__ __launch_bounds__(256) void gemm_k(
    const unsigned short* __restrict__ h, const float* hn,
    const float* __restrict__ Wself, const float* __restrict__ Wneigh,
    const float* __restrict__ bias, float* out, int n) {
    __shared__ unsigned short Bsw[32768];  // 64 KB fragment-order B
    int tid = threadIdx.x;
#pragma unroll
    for (int i = 0; i < 16; ++i) {
        int q = tid + i * 256;
        int l = q & 63;
        int kb = ((q >> 9) << 5) + ((l >> 4) << 3);
        int nn = (((q >> 6) & 7) << 4) + (l & 15);
        const float* Wp = (kb < 128) ? (Wself + (size_t)kb * 128 + nn)
                                     : (Wneigh + (size_t)(kb - 128) * 128 + nn);
        unsigned tmp[4];
#pragma unroll
        for (int j = 0; j < 4; ++j) {
            float v0 = Wp[(2 * j) * 128];
            float v1 = Wp[(2 * j + 1) * 128];
            tmp[j] = (unsigned)f2bf(v0) | ((unsigned)f2bf(v1) << 16);
        }
        uint4 w; w.x = tmp[0]; w.y = tmp[1]; w.z = tmp[2]; w.w = tmp[3];
        *(uint4*)&Bsw[q * 8] = w;
    }
    __syncthreads();

    int wave = tid >> 6, lane = tid & 63;
    int quad = lane >> 4, mrow = lane & 15;
    int r0 = blockIdx.x * 128 + wave * 32;
    int rA0 = min(r0 + mrow, n - 1);
    int rA1 = min(r0 + 16 + mrow, n - 1);

    f32x4 zero = {0.0f, 0.0f, 0.0f, 0.0f};
    f32x4 acc[2][8];
#pragma unroll
    for (int a = 0; a < 2; ++a)
#pragma unroll
        for (int t = 0; t < 8; ++t) acc[a][t] = zero;

#pragma unroll
    for (int s = 0; s < 8; ++s) {
        int kb = s * 32 + quad * 8;
        short8 a0, a1;
        if (s < 4) {
            a0 = *(const short8*)(h + (size_t)rA0 * 128 + kb);
            a1 = *(const short8*)(h + (size_t)rA1 * 128 + kb);
        } else {
            int kk = kb - 128;
            const f32x4* p0 = (const f32x4*)(hn + (size_t)rA0 * 128 + kk);
            const f32x4* p1 = (const f32x4*)(hn + (size_t)rA1 * 128 + kk);
            f32x4 u00 = p0[0], u01 = p0[1];
            f32x4 u10 = p1[0], u11 = p1[1];
#pragma unroll
            for (int j = 0; j < 4; ++j) {
                a0[j]     = (short)f2bf(u00[j]);
                a0[j + 4] = (short)f2bf(u01[j]);
                a1[j]     = (short)f2bf(u10[j]);
                a1[j + 4] = (short)f2bf(u11[j]);
            }
        }
#pragma unroll
        for (int t = 0; t < 8; ++t) {
            short8 b = *(const short8*)(Bsw + ((size_t)(s * 8 + t) * 64 + lane) * 8);
            acc[0][t] = __builtin_amdgcn_mfma_f32_16x16x32_bf16(a0, b, acc[0][t], 0, 0, 0);
            acc[1][t] = __builtin_amdgcn_mfma_f32_16x16x32_bf16(a1, b, acc[1][t], 0, 0, 0);
        }
    }

    float bi[8];
#pragma unroll
    for (int t = 0; t < 8; ++t) bi[t] = bias[t * 16 + mrow];
#pragma unroll
    for (int tm = 0; tm < 2; ++tm) {
#pragma unroll
        for (int i = 0; i < 4; ++i) {
            int row = r0 + tm * 16 + quad * 4 + i;
            if (row < n) {
#pragma unroll
                for (int t = 0; t < 8; ++t) {
                    int col = t * 16 + mrow;
                    float xv = acc[tm][t][i] + bi[t] + bf2f(h[(size_t)row * 128 + col]);
                    float g = 0.5f * xv * (1.0f + erff(xv * 0.70710678f));
                    out[(size_t)row * 128 + col] = g;
                }
            }
        }
    }
}

extern "C" void kernel_launch(void* const* d_in, const int* in_sizes, int n_in,
                              void* d_out, int out_size, void* d_ws, size_t ws_size,
                              hipStream_t stream) {
    const float* features = (const float*)d_in[0];
    const int* src = (const int*)d_in[1];
    const int* dst = (const int*)d_in[2];
    const float* gamma = (const float*)d_in[3];
    const float* beta = (const float*)d_in[4];
    const float* Wself = (const float*)d_in[5];
    const float* Wneigh = (const float*)d_in[6];
    const float* bias = (const float*)d_in[7];
    int n = in_sizes[0] / DD;
    int nE = in_sizes[1];

    auto align1k = [](size_t x) { return (x + 1023) & ~(size_t)1023; };
    char* ws = (char*)d_ws;
    size_t off = 0;
    float* stats = (float*)(ws + off);       off += 1024;
    int* deg     = (int*)(ws + off);         off += align1k((size_t)n * 4);
    int* offsets = (int*)(ws + off);         off += align1k((size_t)(n + 1) * 4);
    int* cursor  = (int*)(ws + off);         off += align1k((size_t)n * 4);
    int* csr     = (int*)(ws + off);         off += align1k((size_t)nE * 4);
    unsigned short* hbuf = (unsigned short*)(ws + off);  // n*128 bf16
    float* hn = (float*)d_out;  // h_neigh fp32 staged in the output buffer

    hipMemsetAsync(stats, 0, 1024, stream);
    hipMemsetAsync(deg, 0, (size_t)n * 4, stream);

    bn_stats_k<<<1024, 256, 0, stream>>>((const float4*)features, stats, n);
    normalize_k<<<(n + 7) / 8, 256, 0, stream>>>(
        (const float4*)features, stats, (const float4*)gamma,
        (const float4*)beta, (uint2*)hbuf, n, 1.0f / (float)n);
    hist_k<<<(nE + 255) / 256, 256, 0, stream>>>(dst, deg, nE);
    scan_k<<<1, 1024, 0, stream>>>(deg, offsets, cursor, n);
    bin_k<<<(nE + 255) / 256, 256, 0, stream>>>(src, dst, cursor, csr, nE);
    pull_k<<<(n * 64 + 255) / 256, 256, 0, stream>>>(
        offsets, csr, (const unsigned*)hbuf, hn, n);
    gemm_k<<<(n + 127) / 128, 256, 0, stream>>>(hbuf, hn, Wself, Wneigh,
        bias, (float*)d_out, n);
}

// Round 3
// 347.634 us; speedup vs baseline: 4.5787x; 1.6460x over previous
//
#include <hip/hip_runtime.h>

#define DD 128

typedef __attribute__((ext_vector_type(8))) short short8;
typedef __attribute__((ext_vector_type(4))) float f32x4;

__device__ inline unsigned short f2bf(float f) {
    unsigned u = __float_as_uint(f);
    unsigned r = u + 0x7fffu + ((u >> 16) & 1u);
    return (unsigned short)(r >> 16);
}
__device__ inline float bf2f(unsigned short s) {
    return __uint_as_float(((unsigned)s) << 16);
}

// ---------------- Kernel 1: BN stats (sum, sumsq per feature) ----------------
__global__ __launch_bounds__(256) void bn_stats_k(
    const float4* __restrict__ x, float* __restrict__ stats, int n) {
    int tid = threadIdx.x;
    int c4 = tid & 31;      // which float4 column (0..31)
    int sub = tid >> 5;     // row-substream within block (0..7)
    float sx = 0.f, sy = 0.f, sz = 0.f, sw = 0.f;
    float qx = 0.f, qy = 0.f, qz = 0.f, qw = 0.f;
    for (int r = blockIdx.x * 8 + sub; r < n; r += gridDim.x * 8) {
        float4 v = x[(size_t)r * 32 + c4];
        sx += v.x; sy += v.y; sz += v.z; sw += v.w;
        qx += v.x * v.x; qy += v.y * v.y; qz += v.z * v.z; qw += v.w * v.w;
    }
    __shared__ float ls[8][256];
    ls[sub][c4 * 4 + 0] = sx; ls[sub][c4 * 4 + 1] = sy;
    ls[sub][c4 * 4 + 2] = sz; ls[sub][c4 * 4 + 3] = sw;
    ls[sub][128 + c4 * 4 + 0] = qx; ls[sub][128 + c4 * 4 + 1] = qy;
    ls[sub][128 + c4 * 4 + 2] = qz; ls[sub][128 + c4 * 4 + 3] = qw;
    __syncthreads();
    float t = 0.f;
#pragma unroll
    for (int k = 0; k < 8; ++k) t += ls[k][tid];
    atomicAdd(&stats[tid], t);
}

// ---------------- Kernel 2: normalize -> h (bf16) ----------------
__global__ __launch_bounds__(256) void normalize_k(
    const float4* __restrict__ x, const float* __restrict__ stats,
    const float4* __restrict__ gamma, const float4* __restrict__ beta,
    uint2* __restrict__ hbuf, int n, float inv_n) {
    int tid = threadIdx.x;
    int c4 = tid & 31, sub = tid >> 5;
    int row = blockIdx.x * 8 + sub;
    if (row >= n) return;
    const float4* s4 = (const float4*)stats;
    float4 sm = s4[c4], sq = s4[32 + c4];
    float4 g = gamma[c4], bt = beta[c4];
    float mx = sm.x * inv_n, my = sm.y * inv_n, mz = sm.z * inv_n, mw = sm.w * inv_n;
    float vx = sq.x * inv_n - mx * mx, vy = sq.y * inv_n - my * my;
    float vz = sq.z * inv_n - mz * mz, vw = sq.w * inv_n - mw * mw;
    float scx = rsqrtf(vx + 1e-5f) * g.x, scy = rsqrtf(vy + 1e-5f) * g.y;
    float scz = rsqrtf(vz + 1e-5f) * g.z, scw = rsqrtf(vw + 1e-5f) * g.w;
    float shx = bt.x - mx * scx, shy = bt.y - my * scy;
    float shz = bt.z - mz * scz, shw = bt.w - mw * scw;
    float4 v = x[(size_t)row * 32 + c4];
    float hx = v.x * scx + shx, hy = v.y * scy + shy;
    float hz = v.z * scz + shz, hw = v.w * scw + shw;
    uint2 o;
    o.x = (unsigned)f2bf(hx) | ((unsigned)f2bf(hy) << 16);
    o.y = (unsigned)f2bf(hz) | ((unsigned)f2bf(hw) << 16);
    hbuf[(size_t)row * 32 + c4] = o;
}

// ---------------- Kernel 3: degree histogram (int atomics) ----------------
__global__ __launch_bounds__(256) void hist_k(
    const int* __restrict__ dst, int* __restrict__ deg, int nE) {
    int e = blockIdx.x * 256 + threadIdx.x;
    if (e < nE) atomicAdd(&deg[dst[e]], 1);
}

// ---------------- Hierarchical scan: tile = 1024 elems / block --------------
// scanA: per-block sum of 1024 degrees
__global__ __launch_bounds__(256) void scanA_k(
    const int* __restrict__ deg, int* __restrict__ bsum, int n) {
    int b = blockIdx.x, t = threadIdx.x;
    int i0 = b * 1024 + t * 4;
    int4 v = {0, 0, 0, 0};
    if (i0 + 3 < n) v = *(const int4*)(deg + i0);
    else {
        if (i0 < n) v.x = deg[i0];
        if (i0 + 1 < n) v.y = deg[i0 + 1];
        if (i0 + 2 < n) v.z = deg[i0 + 2];
        if (i0 + 3 < n) v.w = deg[i0 + 3];
    }
    __shared__ int ls[256];
    ls[t] = v.x + v.y + v.z + v.w;
    __syncthreads();
#pragma unroll
    for (int off = 128; off > 0; off >>= 1) {
        if (t < off) ls[t] += ls[t + off];
        __syncthreads();
    }
    if (t == 0) bsum[b] = ls[0];
}

// scanB: one block scans <=256 block sums -> exclusive prefixes + total
__global__ __launch_bounds__(256) void scanB_k(
    const int* __restrict__ bsum, int* __restrict__ bpref,
    int* __restrict__ offsets, int nb, int n) {
    __shared__ int ls[256];
    int t = threadIdx.x;
    ls[t] = (t < nb) ? bsum[t] : 0;
    __syncthreads();
#pragma unroll
    for (int off = 1; off < 256; off <<= 1) {
        int x = (t >= off) ? ls[t - off] : 0;
        __syncthreads();
        ls[t] += x;
        __syncthreads();
    }
    if (t < nb) bpref[t] = (t == 0) ? 0 : ls[t - 1];
    if (t == nb - 1) offsets[n] = ls[t];  // total edge count
}

// scanC: per-block exclusive scan + block prefix -> offsets & cursor
__global__ __launch_bounds__(256) void scanC_k(
    const int* __restrict__ deg, const int* __restrict__ bpref,
    int* __restrict__ offsets, int* __restrict__ cursor, int n) {
    int b = blockIdx.x, t = threadIdx.x;
    int i0 = b * 1024 + t * 4;
    int4 v = {0, 0, 0, 0};
    if (i0 + 3 < n) v = *(const int4*)(deg + i0);
    else {
        if (i0 < n) v.x = deg[i0];
        if (i0 + 1 < n) v.y = deg[i0 + 1];
        if (i0 + 2 < n) v.z = deg[i0 + 2];
        if (i0 + 3 < n) v.w = deg[i0 + 3];
    }
    int s = v.x + v.y + v.z + v.w;
    __shared__ int ls[256];
    ls[t] = s;
    __syncthreads();
#pragma unroll
    for (int off = 1; off < 256; off <<= 1) {
        int x = (t >= off) ? ls[t - off] : 0;
        __syncthreads();
        ls[t] += x;
        __syncthreads();
    }
    int run = bpref[b] + ((t == 0) ? 0 : ls[t - 1]);
    int4 o;
    o.x = run; o.y = run + v.x; o.z = o.y + v.y; o.w = o.z + v.z;
    if (i0 + 3 < n) {
        *(int4*)(offsets + i0) = o;
        *(int4*)(cursor + i0) = o;
    } else {
        if (i0 < n) { offsets[i0] = o.x; cursor[i0] = o.x; }
        if (i0 + 1 < n) { offsets[i0 + 1] = o.y; cursor[i0 + 1] = o.y; }
        if (i0 + 2 < n) { offsets[i0 + 2] = o.z; cursor[i0 + 2] = o.z; }
        if (i0 + 3 < n) { offsets[i0 + 3] = o.w; cursor[i0 + 3] = o.w; }
    }
}

// ---------------- Kernel 5: bin src indices into CSR ----------------
__global__ __launch_bounds__(256) void bin_k(
    const int* __restrict__ src, const int* __restrict__ dst,
    int* __restrict__ cursor, int* __restrict__ csr, int nE) {
    int e = blockIdx.x * 256 + threadIdx.x;
    if (e < nE) {
        int p = atomicAdd(&cursor[dst[e]], 1);
        csr[p] = src[e];
    }
}

// ---------------- Kernel 6: pull aggregation (no atomics) ----------------
// One wave per dst node; lane l holds features 2l, 2l+1. Writes h_neigh fp32
// (already divided by deg) into d_out (reused; gemm block reads its own rows).
__global__ __launch_bounds__(256) void pull_k(
    const int* __restrict__ offsets, const int* __restrict__ csr,
    const unsigned* __restrict__ h32, float* __restrict__ hn, int n) {
    int wid = (blockIdx.x * 256 + threadIdx.x) >> 6;
    int lane = threadIdx.x & 63;
    if (wid >= n) return;
    int b0 = offsets[wid], b1 = offsets[wid + 1];
    float a0 = 0.f, a1 = 0.f;
    int j = b0;
    for (; j + 2 <= b1; j += 2) {
        int s0 = csr[j], s1 = csr[j + 1];
        unsigned u0 = h32[(size_t)s0 * 64 + lane];
        unsigned u1 = h32[(size_t)s1 * 64 + lane];
        a0 += bf2f((unsigned short)(u0 & 0xffff)) + bf2f((unsigned short)(u1 & 0xffff));
        a1 += bf2f((unsigned short)(u0 >> 16)) + bf2f((unsigned short)(u1 >> 16));
    }
    if (j < b1) {
        int s0 = csr[j];
        unsigned u0 = h32[(size_t)s0 * 64 + lane];
        a0 += bf2f((unsigned short)(u0 & 0xffff));
        a1 += bf2f((unsigned short)(u0 >> 16));
    }
    float rd = (b1 > b0) ? 1.0f / (float)(b1 - b0) : 0.0f;
    float2 o; o.x = a0 * rd; o.y = a1 * rd;
    *(float2*)(hn + (size_t)wid * 128 + lane * 2) = o;
}

// ---------------- Kernel 7: fused GEMM (K=256) + bias + skip + GELU ---------
// C[row][col] = gelu( h@Wself + hn@Wneigh + b + h )
__global__ __launch_bounds__(256) void gemm_k(
    const unsigned short* __restrict__ h, const float* hn,
    const float* __restrict__ Wself, const float* __restrict__ Wneigh,
    const float* __restrict__ bias, float* out, int n) {
    __shared__ unsigned short Bsw[32768];  // 64 KB fragment-order B
    int tid = threadIdx.x;
#pragma unroll
    for (int i = 0; i < 16; ++i) {
        int q = tid + i * 256;
        int l = q & 63;
        int kb = ((q >> 9) << 5) + ((l >> 4) << 3);
        int nn = (((q >> 6) & 7) << 4) + (l & 15);
        const float* Wp = (kb < 128) ? (Wself + (size_t)kb * 128 + nn)
                                     : (Wneigh + (size_t)(kb - 128) * 128 + nn);
        unsigned tmp[4];
#pragma unroll
        for (int j = 0; j < 4; ++j) {
            float v0 = Wp[(2 * j) * 128];
            float v1 = Wp[(2 * j + 1) * 128];
            tmp[j] = (unsigned)f2bf(v0) | ((unsigned)f2bf(v1) << 16);
        }
        uint4 w; w.x = tmp[0]; w.y = tmp[1]; w.z = tmp[2]; w.w = tmp[3];
        *(uint4*)&Bsw[q * 8] = w;
    }
    __syncthreads();

    int wave = tid >> 6, lane = tid & 63;
    int quad = lane >> 4, mrow = lane & 15;
    int r0 = blockIdx.x * 128 + wave * 32;
    int rA0 = min(r0 + mrow, n - 1);
    int rA1 = min(r0 + 16 + mrow, n - 1);

    f32x4 zero = {0.0f, 0.0f, 0.0f, 0.0f};
    f32x4 acc[2][8];
#pragma unroll
    for (int a = 0; a < 2; ++a)
#pragma unroll
        for (int t = 0; t < 8; ++t) acc[a][t] = zero;

#pragma unroll
    for (int s = 0; s < 8; ++s) {
        int kb = s * 32 + quad * 8;
        short8 a0, a1;
        if (s < 4) {
            a0 = *(const short8*)(h + (size_t)rA0 * 128 + kb);
            a1 = *(const short8*)(h + (size_t)rA1 * 128 + kb);
        } else {
            int kk = kb - 128;
            const f32x4* p0 = (const f32x4*)(hn + (size_t)rA0 * 128 + kk);
            const f32x4* p1 = (const f32x4*)(hn + (size_t)rA1 * 128 + kk);
            f32x4 u00 = p0[0], u01 = p0[1];
            f32x4 u10 = p1[0], u11 = p1[1];
#pragma unroll
            for (int j = 0; j < 4; ++j) {
                a0[j]     = (short)f2bf(u00[j]);
                a0[j + 4] = (short)f2bf(u01[j]);
                a1[j]     = (short)f2bf(u10[j]);
                a1[j + 4] = (short)f2bf(u11[j]);
            }
        }
#pragma unroll
        for (int t = 0; t < 8; ++t) {
            short8 b = *(const short8*)(Bsw + ((size_t)(s * 8 + t) * 64 + lane) * 8);
            acc[0][t] = __builtin_amdgcn_mfma_f32_16x16x32_bf16(a0, b, acc[0][t], 0, 0, 0);
            acc[1][t] = __builtin_amdgcn_mfma_f32_16x16x32_bf16(a1, b, acc[1][t], 0, 0, 0);
        }
    }

    float bi[8];
#pragma unroll
    for (int t = 0; t < 8; ++t) bi[t] = bias[t * 16 + mrow];
#pragma unroll
    for (int tm = 0; tm < 2; ++tm) {
#pragma unroll
        for (int i = 0; i < 4; ++i) {
            int row = r0 + tm * 16 + quad * 4 + i;
            if (row < n) {
#pragma unroll
                for (int t = 0; t < 8; ++t) {
                    int col = t * 16 + mrow;
                    float xv = acc[tm][t][i] + bi[t] + bf2f(h[(size_t)row * 128 + col]);
                    float g = 0.5f * xv * (1.0f + erff(xv * 0.70710678f));
                    out[(size_t)row * 128 + col] = g;
                }
            }
        }
    }
}

extern "C" void kernel_launch(void* const* d_in, const int* in_sizes, int n_in,
                              void* d_out, int out_size, void* d_ws, size_t ws_size,
                              hipStream_t stream) {
    const float* features = (const float*)d_in[0];
    const int* src = (const int*)d_in[1];
    const int* dst = (const int*)d_in[2];
    const float* gamma = (const float*)d_in[3];
    const float* beta = (const float*)d_in[4];
    const float* Wself = (const float*)d_in[5];
    const float* Wneigh = (const float*)d_in[6];
    const float* bias = (const float*)d_in[7];
    int n = in_sizes[0] / DD;
    int nE = in_sizes[1];
    int nb = (n + 1023) / 1024;  // scan tiles (<=256 supported by scanB)

    auto align1k = [](size_t x) { return (x + 1023) & ~(size_t)1023; };
    char* ws = (char*)d_ws;
    size_t off = 0;
    float* stats = (float*)(ws + off);       off += 1024;
    int* deg     = (int*)(ws + off);         off += align1k((size_t)n * 4);
    int* offsets = (int*)(ws + off);         off += align1k((size_t)(n + 1) * 4);
    int* cursor  = (int*)(ws + off);         off += align1k((size_t)n * 4);
    int* csr     = (int*)(ws + off);         off += align1k((size_t)nE * 4);
    int* bsum    = (int*)(ws + off);         off += 1024;
    int* bpref   = (int*)(ws + off);         off += 1024;
    unsigned short* hbuf = (unsigned short*)(ws + off);  // n*128 bf16
    float* hn = (float*)d_out;  // h_neigh fp32 staged in the output buffer

    hipMemsetAsync(stats, 0, 1024, stream);
    hipMemsetAsync(deg, 0, (size_t)n * 4, stream);

    bn_stats_k<<<1024, 256, 0, stream>>>((const float4*)features, stats, n);
    normalize_k<<<(n + 7) / 8, 256, 0, stream>>>(
        (const float4*)features, stats, (const float4*)gamma,
        (const float4*)beta, (uint2*)hbuf, n, 1.0f / (float)n);
    hist_k<<<(nE + 255) / 256, 256, 0, stream>>>(dst, deg, nE);
    scanA_k<<<nb, 256, 0, stream>>>(deg, bsum, n);
    scanB_k<<<1, 256, 0, stream>>>(bsum, bpref, offsets, nb, n);
    scanC_k<<<nb, 256, 0, stream>>>(deg, bpref, offsets, cursor, n);
    bin_k<<<(nE + 255) / 256, 256, 0, stream>>>(src, dst, cursor, csr, nE);
    pull_k<<<(n * 64 + 255) / 256, 256, 0, stream>>>(
        offsets, csr, (const unsigned*)hbuf, hn, n);
    gemm_k<<<(n + 127) / 128, 256, 0, stream>>>(hbuf, hn, Wself, Wneigh,
        bias, (float*)d_out, n);
}

// Round 4
// 330.738 us; speedup vs baseline: 4.8126x; 1.0511x over previous
//
#include <hip/hip_runtime.h>

#define DD 128

typedef __attribute__((ext_vector_type(8))) short short8;
typedef __attribute__((ext_vector_type(4))) float f32x4;

__device__ inline unsigned short f2bf(float f) {
    unsigned u = __float_as_uint(f);
    unsigned r = u + 0x7fffu + ((u >> 16) & 1u);
    return (unsigned short)(r >> 16);
}
__device__ inline float bf2f(unsigned short s) {
    return __uint_as_float(((unsigned)s) << 16);
}

// ---------------- Kernel 1: BN stats (sum, sumsq per feature) ----------------
__global__ __launch_bounds__(256) void bn_stats_k(
    const float4* __restrict__ x, float* __restrict__ stats, int n) {
    int tid = threadIdx.x;
    int c4 = tid & 31;
    int sub = tid >> 5;
    float sx = 0.f, sy = 0.f, sz = 0.f, sw = 0.f;
    float qx = 0.f, qy = 0.f, qz = 0.f, qw = 0.f;
    for (int r = blockIdx.x * 8 + sub; r < n; r += gridDim.x * 8) {
        float4 v = x[(size_t)r * 32 + c4];
        sx += v.x; sy += v.y; sz += v.z; sw += v.w;
        qx += v.x * v.x; qy += v.y * v.y; qz += v.z * v.z; qw += v.w * v.w;
    }
    __shared__ float ls[8][256];
    ls[sub][c4 * 4 + 0] = sx; ls[sub][c4 * 4 + 1] = sy;
    ls[sub][c4 * 4 + 2] = sz; ls[sub][c4 * 4 + 3] = sw;
    ls[sub][128 + c4 * 4 + 0] = qx; ls[sub][128 + c4 * 4 + 1] = qy;
    ls[sub][128 + c4 * 4 + 2] = qz; ls[sub][128 + c4 * 4 + 3] = qw;
    __syncthreads();
    float t = 0.f;
#pragma unroll
    for (int k = 0; k < 8; ++k) t += ls[k][tid];
    atomicAdd(&stats[tid], t);
}

// ---------------- Kernel 2: normalize -> h (bf16) ----------------
__global__ __launch_bounds__(256) void normalize_k(
    const float4* __restrict__ x, const float* __restrict__ stats,
    const float4* __restrict__ gamma, const float4* __restrict__ beta,
    uint2* __restrict__ hbuf, int n, float inv_n) {
    int tid = threadIdx.x;
    int c4 = tid & 31, sub = tid >> 5;
    int row = blockIdx.x * 8 + sub;
    if (row >= n) return;
    const float4* s4 = (const float4*)stats;
    float4 sm = s4[c4], sq = s4[32 + c4];
    float4 g = gamma[c4], bt = beta[c4];
    float mx = sm.x * inv_n, my = sm.y * inv_n, mz = sm.z * inv_n, mw = sm.w * inv_n;
    float vx = sq.x * inv_n - mx * mx, vy = sq.y * inv_n - my * my;
    float vz = sq.z * inv_n - mz * mz, vw = sq.w * inv_n - mw * mw;
    float scx = rsqrtf(vx + 1e-5f) * g.x, scy = rsqrtf(vy + 1e-5f) * g.y;
    float scz = rsqrtf(vz + 1e-5f) * g.z, scw = rsqrtf(vw + 1e-5f) * g.w;
    float shx = bt.x - mx * scx, shy = bt.y - my * scy;
    float shz = bt.z - mz * scz, shw = bt.w - mw * scw;
    float4 v = x[(size_t)row * 32 + c4];
    float hx = v.x * scx + shx, hy = v.y * scy + shy;
    float hz = v.z * scz + shz, hw = v.w * scw + shw;
    uint2 o;
    o.x = (unsigned)f2bf(hx) | ((unsigned)f2bf(hy) << 16);
    o.y = (unsigned)f2bf(hz) | ((unsigned)f2bf(hw) << 16);
    hbuf[(size_t)row * 32 + c4] = o;
}

// ---------------- prep: swizzle [Wself;Wneigh] -> bf16 fragment order -------
__global__ __launch_bounds__(256) void prep_k(
    const float* __restrict__ Wself, const float* __restrict__ Wneigh,
    unsigned short* __restrict__ Bpre) {
    int q = blockIdx.x * 256 + threadIdx.x;  // 0..4095
    int l = q & 63;
    int kb = ((q >> 9) << 5) + ((l >> 4) << 3);
    int nn = (((q >> 6) & 7) << 4) + (l & 15);
    const float* Wp = (kb < 128) ? (Wself + (size_t)kb * 128 + nn)
                                 : (Wneigh + (size_t)(kb - 128) * 128 + nn);
    unsigned tmp[4];
#pragma unroll
    for (int j = 0; j < 4; ++j) {
        float v0 = Wp[(2 * j) * 128];
        float v1 = Wp[(2 * j + 1) * 128];
        tmp[j] = (unsigned)f2bf(v0) | ((unsigned)f2bf(v1) << 16);
    }
    uint4 w; w.x = tmp[0]; w.y = tmp[1]; w.z = tmp[2]; w.w = tmp[3];
    *(uint4*)(Bpre + (size_t)q * 8) = w;
}

// ---------------- Kernel 3: degree histogram (int atomics) ----------------
__global__ __launch_bounds__(256) void hist_k(
    const int* __restrict__ dst, int* __restrict__ deg, int nE) {
    int e = blockIdx.x * 256 + threadIdx.x;
    if (e < nE) atomicAdd(&deg[dst[e]], 1);
}

// ---------------- Hierarchical scan: tile = 1024 elems / block --------------
__global__ __launch_bounds__(256) void scanA_k(
    const int* __restrict__ deg, int* __restrict__ bsum, int n) {
    int b = blockIdx.x, t = threadIdx.x;
    int i0 = b * 1024 + t * 4;
    int4 v = {0, 0, 0, 0};
    if (i0 + 3 < n) v = *(const int4*)(deg + i0);
    else {
        if (i0 < n) v.x = deg[i0];
        if (i0 + 1 < n) v.y = deg[i0 + 1];
        if (i0 + 2 < n) v.z = deg[i0 + 2];
        if (i0 + 3 < n) v.w = deg[i0 + 3];
    }
    __shared__ int ls[256];
    ls[t] = v.x + v.y + v.z + v.w;
    __syncthreads();
#pragma unroll
    for (int off = 128; off > 0; off >>= 1) {
        if (t < off) ls[t] += ls[t + off];
        __syncthreads();
    }
    if (t == 0) bsum[b] = ls[0];
}

__global__ __launch_bounds__(256) void scanB_k(
    const int* __restrict__ bsum, int* __restrict__ bpref,
    int* __restrict__ offsets, int nb, int n) {
    __shared__ int ls[256];
    int t = threadIdx.x;
    ls[t] = (t < nb) ? bsum[t] : 0;
    __syncthreads();
#pragma unroll
    for (int off = 1; off < 256; off <<= 1) {
        int x = (t >= off) ? ls[t - off] : 0;
        __syncthreads();
        ls[t] += x;
        __syncthreads();
    }
    if (t < nb) bpref[t] = (t == 0) ? 0 : ls[t - 1];
    if (t == nb - 1) offsets[n] = ls[t];
}

__global__ __launch_bounds__(256) void scanC_k(
    const int* __restrict__ deg, const int* __restrict__ bpref,
    int* __restrict__ offsets, int* __restrict__ cursor, int n) {
    int b = blockIdx.x, t = threadIdx.x;
    int i0 = b * 1024 + t * 4;
    int4 v = {0, 0, 0, 0};
    if (i0 + 3 < n) v = *(const int4*)(deg + i0);
    else {
        if (i0 < n) v.x = deg[i0];
        if (i0 + 1 < n) v.y = deg[i0 + 1];
        if (i0 + 2 < n) v.z = deg[i0 + 2];
        if (i0 + 3 < n) v.w = deg[i0 + 3];
    }
    int s = v.x + v.y + v.z + v.w;
    __shared__ int ls[256];
    ls[t] = s;
    __syncthreads();
#pragma unroll
    for (int off = 1; off < 256; off <<= 1) {
        int x = (t >= off) ? ls[t - off] : 0;
        __syncthreads();
        ls[t] += x;
        __syncthreads();
    }
    int run = bpref[b] + ((t == 0) ? 0 : ls[t - 1]);
    int4 o;
    o.x = run; o.y = run + v.x; o.z = o.y + v.y; o.w = o.z + v.z;
    if (i0 + 3 < n) {
        *(int4*)(offsets + i0) = o;
        *(int4*)(cursor + i0) = o;
    } else {
        if (i0 < n) { offsets[i0] = o.x; cursor[i0] = o.x; }
        if (i0 + 1 < n) { offsets[i0 + 1] = o.y; cursor[i0 + 1] = o.y; }
        if (i0 + 2 < n) { offsets[i0 + 2] = o.z; cursor[i0 + 2] = o.z; }
        if (i0 + 3 < n) { offsets[i0 + 3] = o.w; cursor[i0 + 3] = o.w; }
    }
}

// ---------------- Kernel 5: bin src indices into CSR ----------------
__global__ __launch_bounds__(256) void bin_k(
    const int* __restrict__ src, const int* __restrict__ dst,
    int* __restrict__ cursor, int* __restrict__ csr, int nE) {
    int e = blockIdx.x * 256 + threadIdx.x;
    if (e < nE) {
        int p = atomicAdd(&cursor[dst[e]], 1);
        csr[p] = src[e];
    }
}

// ---------------- Kernel 6: pull aggregation -> bf16 hn in d_out rows -------
// One wave per dst node; lane l accumulates features 2l, 2l+1 in fp32, then
// writes packed bf16 into the FIRST 256 B of that row's own 512 B output slot.
// Race-free: gemm reads a row's hn only from the block that overwrites it.
__global__ __launch_bounds__(256) void pull_k(
    const int* __restrict__ offsets, const int* __restrict__ csr,
    const unsigned* __restrict__ h32, unsigned* outw, int n) {
    int wid = (blockIdx.x * 256 + threadIdx.x) >> 6;
    int lane = threadIdx.x & 63;
    if (wid >= n) return;
    int b0 = offsets[wid], b1 = offsets[wid + 1];
    float a0 = 0.f, a1 = 0.f;
    int j = b0;
    for (; j + 4 <= b1; j += 4) {
        int s0 = csr[j], s1 = csr[j + 1], s2 = csr[j + 2], s3 = csr[j + 3];
        unsigned u0 = h32[(size_t)s0 * 64 + lane];
        unsigned u1 = h32[(size_t)s1 * 64 + lane];
        unsigned u2 = h32[(size_t)s2 * 64 + lane];
        unsigned u3 = h32[(size_t)s3 * 64 + lane];
        a0 += bf2f((unsigned short)(u0 & 0xffff)) + bf2f((unsigned short)(u1 & 0xffff))
            + bf2f((unsigned short)(u2 & 0xffff)) + bf2f((unsigned short)(u3 & 0xffff));
        a1 += bf2f((unsigned short)(u0 >> 16)) + bf2f((unsigned short)(u1 >> 16))
            + bf2f((unsigned short)(u2 >> 16)) + bf2f((unsigned short)(u3 >> 16));
    }
    for (; j < b1; ++j) {
        int s0 = csr[j];
        unsigned u0 = h32[(size_t)s0 * 64 + lane];
        a0 += bf2f((unsigned short)(u0 & 0xffff));
        a1 += bf2f((unsigned short)(u0 >> 16));
    }
    float rd = (b1 > b0) ? 1.0f / (float)(b1 - b0) : 0.0f;
    unsigned o = (unsigned)f2bf(a0 * rd) | ((unsigned)f2bf(a1 * rd) << 16);
    outw[(size_t)wid * 128 + lane] = o;  // byte offset wid*512 + lane*4
}

// ---------------- Kernel 7: fused GEMM (K=256, M=256/block) -----------------
// C[row][col] = gelu( h@Wself + hn@Wneigh + b + h ); hn = bf16 in out rows.
__global__ __launch_bounds__(256, 2) void gemm_k(
    const unsigned short* __restrict__ h, const unsigned short* __restrict__ Bpre,
    const float* __restrict__ bias, float* out, int n) {
    __shared__ unsigned short Bsw[32768];  // 64 KB fragment-order B
    int tid = threadIdx.x, wave = tid >> 6, lane = tid & 63;
    // stage pre-swizzled B: 16 x global_load_lds width-16, coalesced
#pragma unroll
    for (int i = 0; i < 16; ++i) {
        int qb = i * 256 + wave * 64;
        __builtin_amdgcn_global_load_lds(
            (const __attribute__((address_space(1))) void*)(Bpre + (size_t)(qb + lane) * 8),
            (__attribute__((address_space(3))) void*)(Bsw + (size_t)qb * 8),
            16, 0, 0);
    }
    __syncthreads();

    const unsigned short* hn = (const unsigned short*)out;  // aliased on purpose
    int quad = lane >> 4, mrow = lane & 15;
    int r0 = blockIdx.x * 256 + wave * 64;
    int rA[4];
#pragma unroll
    for (int m = 0; m < 4; ++m) rA[m] = min(r0 + m * 16 + mrow, n - 1);

    f32x4 zero = {0.0f, 0.0f, 0.0f, 0.0f};
    f32x4 acc[4][8];
#pragma unroll
    for (int m = 0; m < 4; ++m)
#pragma unroll
        for (int t = 0; t < 8; ++t) acc[m][t] = zero;

#pragma unroll
    for (int s = 0; s < 8; ++s) {
        int kb = s * 32 + quad * 8;
        short8 af[4];
        if (s < 4) {
#pragma unroll
            for (int m = 0; m < 4; ++m)
                af[m] = *(const short8*)(h + (size_t)rA[m] * 128 + kb);
        } else {
            int kk = kb - 128;
#pragma unroll
            for (int m = 0; m < 4; ++m)
                af[m] = *(const short8*)(hn + (size_t)rA[m] * 256 + kk);
        }
#pragma unroll
        for (int t = 0; t < 8; ++t) {
            short8 b = *(const short8*)(Bsw + ((size_t)(s * 8 + t) * 64 + lane) * 8);
#pragma unroll
            for (int m = 0; m < 4; ++m)
                acc[m][t] = __builtin_amdgcn_mfma_f32_16x16x32_bf16(af[m], b, acc[m][t], 0, 0, 0);
        }
    }

    float bi[8];
#pragma unroll
    for (int t = 0; t < 8; ++t) bi[t] = bias[t * 16 + mrow];
#pragma unroll
    for (int m = 0; m < 4; ++m) {
#pragma unroll
        for (int i = 0; i < 4; ++i) {
            int row = r0 + m * 16 + quad * 4 + i;
            if (row < n) {
#pragma unroll
                for (int t = 0; t < 8; ++t) {
                    int col = t * 16 + mrow;
                    float xv = acc[m][t][i] + bi[t] + bf2f(h[(size_t)row * 128 + col]);
                    float g = 0.5f * xv * (1.0f + erff(xv * 0.70710678f));
                    out[(size_t)row * 128 + col] = g;
                }
            }
        }
    }
}

extern "C" void kernel_launch(void* const* d_in, const int* in_sizes, int n_in,
                              void* d_out, int out_size, void* d_ws, size_t ws_size,
                              hipStream_t stream) {
    const float* features = (const float*)d_in[0];
    const int* src = (const int*)d_in[1];
    const int* dst = (const int*)d_in[2];
    const float* gamma = (const float*)d_in[3];
    const float* beta = (const float*)d_in[4];
    const float* Wself = (const float*)d_in[5];
    const float* Wneigh = (const float*)d_in[6];
    const float* bias = (const float*)d_in[7];
    int n = in_sizes[0] / DD;
    int nE = in_sizes[1];
    int nb = (n + 1023) / 1024;  // <=256 (scanB limit)

    auto align1k = [](size_t x) { return (x + 1023) & ~(size_t)1023; };
    char* ws = (char*)d_ws;
    size_t off = 0;
    float* stats = (float*)(ws + off);       off += 1024;
    int* deg     = (int*)(ws + off);         off += align1k((size_t)n * 4);
    int* offsets = (int*)(ws + off);         off += align1k((size_t)(n + 1) * 4);
    int* cursor  = (int*)(ws + off);         off += align1k((size_t)n * 4);
    int* csr     = (int*)(ws + off);         off += align1k((size_t)nE * 4);
    int* bsum    = (int*)(ws + off);         off += 1024;
    int* bpref   = (int*)(ws + off);         off += 1024;
    unsigned short* Bpre = (unsigned short*)(ws + off); off += 65536;
    unsigned short* hbuf = (unsigned short*)(ws + off);  // n*128 bf16

    hipMemsetAsync(stats, 0, 1024, stream);
    hipMemsetAsync(deg, 0, (size_t)n * 4, stream);

    prep_k<<<16, 256, 0, stream>>>(Wself, Wneigh, Bpre);
    bn_stats_k<<<1024, 256, 0, stream>>>((const float4*)features, stats, n);
    normalize_k<<<(n + 7) / 8, 256, 0, stream>>>(
        (const float4*)features, stats, (const float4*)gamma,
        (const float4*)beta, (uint2*)hbuf, n, 1.0f / (float)n);
    hist_k<<<(nE + 255) / 256, 256, 0, stream>>>(dst, deg, nE);
    scanA_k<<<nb, 256, 0, stream>>>(deg, bsum, n);
    scanB_k<<<1, 256, 0, stream>>>(bsum, bpref, offsets, nb, n);
    scanC_k<<<nb, 256, 0, stream>>>(deg, bpref, offsets, cursor, n);
    bin_k<<<(nE + 255) / 256, 256, 0, stream>>>(src, dst, cursor, csr, nE);
    pull_k<<<(n * 64 + 255) / 256, 256, 0, stream>>>(
        offsets, csr, (const unsigned*)hbuf, (unsigned*)d_out, n);
    gemm_k<<<(n + 255) / 256, 256, 0, stream>>>(hbuf, Bpre, bias, (float*)d_out, n);
}

// Round 5
// 280.644 us; speedup vs baseline: 5.6717x; 1.1785x over previous
//
#include <hip/hip_runtime.h>

#define DD 128

typedef __attribute__((ext_vector_type(8))) short short8;
typedef __attribute__((ext_vector_type(4))) float f32x4;

__device__ inline unsigned short f2bf(float f) {
    unsigned u = __float_as_uint(f);
    unsigned r = u + 0x7fffu + ((u >> 16) & 1u);
    return (unsigned short)(r >> 16);
}
__device__ inline float bf2f(unsigned short s) {
    return __uint_as_float(((unsigned)s) << 16);
}

// ---------------- phase1: bn_stats (1024 blks) + hist + prep ----------------
__global__ __launch_bounds__(256) void phase1_k(
    const float4* __restrict__ x, float* __restrict__ stats, int n,
    const int* __restrict__ dst, int* __restrict__ deg, int nE, int nbHist,
    const float* __restrict__ Wself, const float* __restrict__ Wneigh,
    unsigned short* __restrict__ Bpre) {
    int b = blockIdx.x, tid = threadIdx.x;
    if (b < 1024) {
        // ---- BN stats: sum & sumsq per feature ----
        int c4 = tid & 31, sub = tid >> 5;
        float sx = 0.f, sy = 0.f, sz = 0.f, sw = 0.f;
        float qx = 0.f, qy = 0.f, qz = 0.f, qw = 0.f;
        for (int r = b * 8 + sub; r < n; r += 1024 * 8) {
            float4 v = x[(size_t)r * 32 + c4];
            sx += v.x; sy += v.y; sz += v.z; sw += v.w;
            qx += v.x * v.x; qy += v.y * v.y; qz += v.z * v.z; qw += v.w * v.w;
        }
        __shared__ float ls[8][256];
        ls[sub][c4 * 4 + 0] = sx; ls[sub][c4 * 4 + 1] = sy;
        ls[sub][c4 * 4 + 2] = sz; ls[sub][c4 * 4 + 3] = sw;
        ls[sub][128 + c4 * 4 + 0] = qx; ls[sub][128 + c4 * 4 + 1] = qy;
        ls[sub][128 + c4 * 4 + 2] = qz; ls[sub][128 + c4 * 4 + 3] = qw;
        __syncthreads();
        float t = 0.f;
#pragma unroll
        for (int k = 0; k < 8; ++k) t += ls[k][tid];
        atomicAdd(&stats[tid], t);
    } else if (b < 1024 + nbHist) {
        // ---- degree histogram ----
        int e = (b - 1024) * 256 + tid;
        if (e < nE) atomicAdd(&deg[dst[e]], 1);
    } else {
        // ---- prep: swizzle [Wself+I; Wneigh] -> bf16 MFMA fragment order ----
        int q = (b - 1024 - nbHist) * 256 + tid;  // 0..4095
        int l = q & 63;
        int kb = ((q >> 9) << 5) + ((l >> 4) << 3);
        int nn = (((q >> 6) & 7) << 4) + (l & 15);
        bool self = (kb < 128);
        const float* Wp = self ? (Wself + (size_t)kb * 128 + nn)
                               : (Wneigh + (size_t)(kb - 128) * 128 + nn);
        unsigned tmp[4];
#pragma unroll
        for (int j = 0; j < 4; ++j) {
            float v0 = Wp[(2 * j) * 128];
            float v1 = Wp[(2 * j + 1) * 128];
            if (self) {  // fold skip connection: W_self + I
                if (kb + 2 * j == nn) v0 += 1.0f;
                if (kb + 2 * j + 1 == nn) v1 += 1.0f;
            }
            tmp[j] = (unsigned)f2bf(v0) | ((unsigned)f2bf(v1) << 16);
        }
        uint4 w; w.x = tmp[0]; w.y = tmp[1]; w.z = tmp[2]; w.w = tmp[3];
        *(uint4*)(Bpre + (size_t)q * 8) = w;
    }
}

// ---------------- phase2: normalize (nbNorm blks) + scanA -------------------
__global__ __launch_bounds__(256) void phase2_k(
    const float4* __restrict__ x, const float* __restrict__ stats,
    const float4* __restrict__ gamma, const float4* __restrict__ beta,
    uint2* __restrict__ hbuf, int n, float inv_n, int nbNorm,
    const int* __restrict__ deg, int* __restrict__ bsum) {
    int b = blockIdx.x, tid = threadIdx.x;
    if (b < nbNorm) {
        int c4 = tid & 31, sub = tid >> 5;
        int row = b * 8 + sub;
        if (row >= n) return;
        const float4* s4 = (const float4*)stats;
        float4 sm = s4[c4], sq = s4[32 + c4];
        float4 g = gamma[c4], bt = beta[c4];
        float mx = sm.x * inv_n, my = sm.y * inv_n, mz = sm.z * inv_n, mw = sm.w * inv_n;
        float vx = sq.x * inv_n - mx * mx, vy = sq.y * inv_n - my * my;
        float vz = sq.z * inv_n - mz * mz, vw = sq.w * inv_n - mw * mw;
        float scx = rsqrtf(vx + 1e-5f) * g.x, scy = rsqrtf(vy + 1e-5f) * g.y;
        float scz = rsqrtf(vz + 1e-5f) * g.z, scw = rsqrtf(vw + 1e-5f) * g.w;
        float shx = bt.x - mx * scx, shy = bt.y - my * scy;
        float shz = bt.z - mz * scz, shw = bt.w - mw * scw;
        float4 v = x[(size_t)row * 32 + c4];
        float hx = v.x * scx + shx, hy = v.y * scy + shy;
        float hz = v.z * scz + shz, hw = v.w * scw + shw;
        uint2 o;
        o.x = (unsigned)f2bf(hx) | ((unsigned)f2bf(hy) << 16);
        o.y = (unsigned)f2bf(hz) | ((unsigned)f2bf(hw) << 16);
        hbuf[(size_t)row * 32 + c4] = o;
    } else {
        // ---- scanA: per-block sum of 1024 degrees ----
        int bb = b - nbNorm;
        int i0 = bb * 1024 + tid * 4;
        int4 v = {0, 0, 0, 0};
        if (i0 + 3 < n) v = *(const int4*)(deg + i0);
        else {
            if (i0 < n) v.x = deg[i0];
            if (i0 + 1 < n) v.y = deg[i0 + 1];
            if (i0 + 2 < n) v.z = deg[i0 + 2];
        }
        __shared__ int ls[256];
        ls[tid] = v.x + v.y + v.z + v.w;
        __syncthreads();
#pragma unroll
        for (int off = 128; off > 0; off >>= 1) {
            if (tid < off) ls[tid] += ls[tid + off];
            __syncthreads();
        }
        if (tid == 0) bsum[bb] = ls[0];
    }
}

__global__ __launch_bounds__(256) void scanB_k(
    const int* __restrict__ bsum, int* __restrict__ bpref,
    int* __restrict__ offsets, int nb, int n) {
    __shared__ int ls[256];
    int t = threadIdx.x;
    ls[t] = (t < nb) ? bsum[t] : 0;
    __syncthreads();
#pragma unroll
    for (int off = 1; off < 256; off <<= 1) {
        int x = (t >= off) ? ls[t - off] : 0;
        __syncthreads();
        ls[t] += x;
        __syncthreads();
    }
    if (t < nb) bpref[t] = (t == 0) ? 0 : ls[t - 1];
    if (t == nb - 1) offsets[n] = ls[t];
}

__global__ __launch_bounds__(256) void scanC_k(
    const int* __restrict__ deg, const int* __restrict__ bpref,
    int* __restrict__ offsets, int* __restrict__ cursor, int n) {
    int b = blockIdx.x, t = threadIdx.x;
    int i0 = b * 1024 + t * 4;
    int4 v = {0, 0, 0, 0};
    if (i0 + 3 < n) v = *(const int4*)(deg + i0);
    else {
        if (i0 < n) v.x = deg[i0];
        if (i0 + 1 < n) v.y = deg[i0 + 1];
        if (i0 + 2 < n) v.z = deg[i0 + 2];
    }
    int s = v.x + v.y + v.z + v.w;
    __shared__ int ls[256];
    ls[t] = s;
    __syncthreads();
#pragma unroll
    for (int off = 1; off < 256; off <<= 1) {
        int x = (t >= off) ? ls[t - off] : 0;
        __syncthreads();
        ls[t] += x;
        __syncthreads();
    }
    int run = bpref[b] + ((t == 0) ? 0 : ls[t - 1]);
    int4 o;
    o.x = run; o.y = run + v.x; o.z = o.y + v.y; o.w = o.z + v.z;
    if (i0 + 3 < n) {
        *(int4*)(offsets + i0) = o;
        *(int4*)(cursor + i0) = o;
    } else {
        if (i0 < n) { offsets[i0] = o.x; cursor[i0] = o.x; }
        if (i0 + 1 < n) { offsets[i0 + 1] = o.y; cursor[i0 + 1] = o.y; }
        if (i0 + 2 < n) { offsets[i0 + 2] = o.z; cursor[i0 + 2] = o.z; }
    }
}

// ---------------- bin: src indices into CSR ----------------
__global__ __launch_bounds__(256) void bin_k(
    const int* __restrict__ src, const int* __restrict__ dst,
    int* __restrict__ cursor, int* __restrict__ csr, int nE) {
    int e = blockIdx.x * 256 + threadIdx.x;
    if (e < nE) {
        int p = atomicAdd(&cursor[dst[e]], 1);
        csr[p] = src[e];
    }
}

// ---------------- pull: per-node mean of h[src] -> bf16 hn in d_out ---------
__global__ __launch_bounds__(256) void pull_k(
    const int* __restrict__ offsets, const int* __restrict__ csr,
    const unsigned* __restrict__ h32, unsigned* outw, int n) {
    int wid = (blockIdx.x * 256 + threadIdx.x) >> 6;
    int lane = threadIdx.x & 63;
    if (wid >= n) return;
    int b0 = offsets[wid], b1 = offsets[wid + 1];
    float a0 = 0.f, a1 = 0.f;
    int j = b0;
    for (; j + 8 <= b1; j += 8) {
        unsigned u[8];
#pragma unroll
        for (int q = 0; q < 8; ++q) u[q] = h32[(size_t)csr[j + q] * 64 + lane];
#pragma unroll
        for (int q = 0; q < 8; ++q) {
            a0 += bf2f((unsigned short)(u[q] & 0xffff));
            a1 += bf2f((unsigned short)(u[q] >> 16));
        }
    }
    for (; j + 2 <= b1; j += 2) {
        unsigned u0 = h32[(size_t)csr[j] * 64 + lane];
        unsigned u1 = h32[(size_t)csr[j + 1] * 64 + lane];
        a0 += bf2f((unsigned short)(u0 & 0xffff)) + bf2f((unsigned short)(u1 & 0xffff));
        a1 += bf2f((unsigned short)(u0 >> 16)) + bf2f((unsigned short)(u1 >> 16));
    }
    if (j < b1) {
        unsigned u0 = h32[(size_t)csr[j] * 64 + lane];
        a0 += bf2f((unsigned short)(u0 & 0xffff));
        a1 += bf2f((unsigned short)(u0 >> 16));
    }
    float rd = (b1 > b0) ? 1.0f / (float)(b1 - b0) : 0.0f;
    unsigned o = (unsigned)f2bf(a0 * rd) | ((unsigned)f2bf(a1 * rd) << 16);
    outw[(size_t)wid * 128 + lane] = o;  // byte offset wid*512 + lane*4
}

// ---------------- gemm: C = gelu_tanh( h@(Ws+I) + hn@Wn + b ) ---------------
__global__ __launch_bounds__(256, 2) void gemm_k(
    const unsigned short* __restrict__ h, const unsigned short* __restrict__ Bpre,
    const float* __restrict__ bias, float* out, int n) {
    __shared__ unsigned short Bsw[32768];  // 64 KB fragment-order B
    int tid = threadIdx.x, wave = tid >> 6, lane = tid & 63;
#pragma unroll
    for (int i = 0; i < 16; ++i) {
        int qb = i * 256 + wave * 64;
        __builtin_amdgcn_global_load_lds(
            (const __attribute__((address_space(1))) void*)(Bpre + (size_t)(qb + lane) * 8),
            (__attribute__((address_space(3))) void*)(Bsw + (size_t)qb * 8),
            16, 0, 0);
    }
    __syncthreads();

    const unsigned short* hn = (const unsigned short*)out;  // aliased on purpose
    int quad = lane >> 4, mrow = lane & 15;
    int r0 = blockIdx.x * 256 + wave * 64;
    int rA[4];
#pragma unroll
    for (int m = 0; m < 4; ++m) rA[m] = min(r0 + m * 16 + mrow, n - 1);

    f32x4 zero = {0.0f, 0.0f, 0.0f, 0.0f};
    f32x4 acc[4][8];
#pragma unroll
    for (int m = 0; m < 4; ++m)
#pragma unroll
        for (int t = 0; t < 8; ++t) acc[m][t] = zero;

#pragma unroll
    for (int s = 0; s < 8; ++s) {
        int kb = s * 32 + quad * 8;
        short8 af[4];
        if (s < 4) {
#pragma unroll
            for (int m = 0; m < 4; ++m)
                af[m] = *(const short8*)(h + (size_t)rA[m] * 128 + kb);
        } else {
            int kk = kb - 128;
#pragma unroll
            for (int m = 0; m < 4; ++m)
                af[m] = *(const short8*)(hn + (size_t)rA[m] * 256 + kk);
        }
#pragma unroll
        for (int t = 0; t < 8; ++t) {
            short8 b = *(const short8*)(Bsw + ((size_t)(s * 8 + t) * 64 + lane) * 8);
#pragma unroll
            for (int m = 0; m < 4; ++m)
                acc[m][t] = __builtin_amdgcn_mfma_f32_16x16x32_bf16(af[m], b, acc[m][t], 0, 0, 0);
        }
    }

    float bi[8];
#pragma unroll
    for (int t = 0; t < 8; ++t) bi[t] = bias[t * 16 + mrow];
#pragma unroll
    for (int m = 0; m < 4; ++m) {
#pragma unroll
        for (int i = 0; i < 4; ++i) {
            int row = r0 + m * 16 + quad * 4 + i;
            if (row < n) {
#pragma unroll
                for (int t = 0; t < 8; ++t) {
                    int col = t * 16 + mrow;
                    float xv = acc[m][t][i] + bi[t];
                    // tanh-approx GELU (max abs err ~3e-3 vs exact)
                    float x2 = xv * xv;
                    float u = 0.7978845608f * xv * (1.0f + 0.044715f * x2);
                    float e = __expf(2.0f * u);  // inf-safe form below
                    float th = 1.0f - 2.0f * __builtin_amdgcn_rcpf(e + 1.0f);
                    out[(size_t)row * 128 + col] = 0.5f * xv * (1.0f + th);
                }
            }
        }
    }
}

extern "C" void kernel_launch(void* const* d_in, const int* in_sizes, int n_in,
                              void* d_out, int out_size, void* d_ws, size_t ws_size,
                              hipStream_t stream) {
    const float* features = (const float*)d_in[0];
    const int* src = (const int*)d_in[1];
    const int* dst = (const int*)d_in[2];
    const float* gamma = (const float*)d_in[3];
    const float* beta = (const float*)d_in[4];
    const float* Wself = (const float*)d_in[5];
    const float* Wneigh = (const float*)d_in[6];
    const float* bias = (const float*)d_in[7];
    int n = in_sizes[0] / DD;
    int nE = in_sizes[1];
    int nb = (n + 1023) / 1024;        // scan tiles (<=256)
    int nbHist = (nE + 255) / 256;
    int nbNorm = (n + 7) / 8;

    auto align1k = [](size_t x) { return (x + 1023) & ~(size_t)1023; };
    char* ws = (char*)d_ws;
    size_t off = 0;
    float* stats = (float*)(ws + off);       off += 1024;
    int* deg     = (int*)(ws + off);         off += align1k((size_t)n * 4);  // contiguous w/ stats
    int* offsets = (int*)(ws + off);         off += align1k((size_t)(n + 1) * 4);
    int* cursor  = (int*)(ws + off);         off += align1k((size_t)n * 4);
    int* csr     = (int*)(ws + off);         off += align1k((size_t)nE * 4);
    int* bsum    = (int*)(ws + off);         off += 1024;
    int* bpref   = (int*)(ws + off);         off += 1024;
    unsigned short* Bpre = (unsigned short*)(ws + off); off += 65536;
    unsigned short* hbuf = (unsigned short*)(ws + off);  // n*128 bf16

    // stats (1024 B) and deg are contiguous: one memset covers both
    hipMemsetAsync(stats, 0, 1024 + (size_t)n * 4, stream);

    phase1_k<<<1024 + nbHist + 16, 256, 0, stream>>>(
        (const float4*)features, stats, n, dst, deg, nE, nbHist,
        Wself, Wneigh, Bpre);
    phase2_k<<<nbNorm + nb, 256, 0, stream>>>(
        (const float4*)features, stats, (const float4*)gamma,
        (const float4*)beta, (uint2*)hbuf, n, 1.0f / (float)n, nbNorm,
        deg, bsum);
    scanB_k<<<1, 256, 0, stream>>>(bsum, bpref, offsets, nb, n);
    scanC_k<<<nb, 256, 0, stream>>>(deg, bpref, offsets, cursor, n);
    bin_k<<<nbHist, 256, 0, stream>>>(src, dst, cursor, csr, nE);
    pull_k<<<(n * 64 + 255) / 256, 256, 0, stream>>>(
        offsets, csr, (const unsigned*)hbuf, (unsigned*)d_out, n);
    gemm_k<<<(n + 255) / 256, 256, 0, stream>>>(hbuf, Bpre, bias, (float*)d_out, n);
}

// Round 6
// 268.672 us; speedup vs baseline: 5.9244x; 1.0446x over previous
//
#include <hip/hip_runtime.h>

#define DD 128

typedef __attribute__((ext_vector_type(8))) short short8;
typedef __attribute__((ext_vector_type(4))) float f32x4;

__device__ inline unsigned short f2bf(float f) {
    unsigned u = __float_as_uint(f);
    unsigned r = u + 0x7fffu + ((u >> 16) & 1u);
    return (unsigned short)(r >> 16);
}
__device__ inline float bf2f(unsigned short s) {
    return __uint_as_float(((unsigned)s) << 16);
}

// ---------------- phase1: prep (16) + bn_stats (1024, sharded) + hist -------
__global__ __launch_bounds__(256) void phase1_k(
    const float4* __restrict__ x, float* __restrict__ stats16, int n,
    const int* __restrict__ dst, int* __restrict__ deg, int nE,
    const float* __restrict__ Wself, const float* __restrict__ Wneigh,
    unsigned short* __restrict__ Bpre) {
    int b = blockIdx.x, tid = threadIdx.x;
    if (b < 16) {
        // ---- prep: swizzle [Wself+I; Wneigh] -> bf16 MFMA fragment order ----
        int q = b * 256 + tid;  // 0..4095
        int l = q & 63;
        int kb = ((q >> 9) << 5) + ((l >> 4) << 3);
        int nn = (((q >> 6) & 7) << 4) + (l & 15);
        bool self = (kb < 128);
        const float* Wp = self ? (Wself + (size_t)kb * 128 + nn)
                               : (Wneigh + (size_t)(kb - 128) * 128 + nn);
        unsigned tmp[4];
#pragma unroll
        for (int j = 0; j < 4; ++j) {
            float v0 = Wp[(2 * j) * 128];
            float v1 = Wp[(2 * j + 1) * 128];
            if (self) {  // fold skip connection: W_self + I
                if (kb + 2 * j == nn) v0 += 1.0f;
                if (kb + 2 * j + 1 == nn) v1 += 1.0f;
            }
            tmp[j] = (unsigned)f2bf(v0) | ((unsigned)f2bf(v1) << 16);
        }
        uint4 w; w.x = tmp[0]; w.y = tmp[1]; w.z = tmp[2]; w.w = tmp[3];
        *(uint4*)(Bpre + (size_t)q * 8) = w;
    } else if (b < 16 + 1024) {
        // ---- BN stats: sum & sumsq per feature, atomics sharded x16 ----
        int bb = b - 16;
        int c4 = tid & 31, sub = tid >> 5;
        float sx = 0.f, sy = 0.f, sz = 0.f, sw = 0.f;
        float qx = 0.f, qy = 0.f, qz = 0.f, qw = 0.f;
        for (int r = bb * 8 + sub; r < n; r += 1024 * 8) {
            float4 v = x[(size_t)r * 32 + c4];
            sx += v.x; sy += v.y; sz += v.z; sw += v.w;
            qx += v.x * v.x; qy += v.y * v.y; qz += v.z * v.z; qw += v.w * v.w;
        }
        __shared__ float ls[8][256];
        ls[sub][c4 * 4 + 0] = sx; ls[sub][c4 * 4 + 1] = sy;
        ls[sub][c4 * 4 + 2] = sz; ls[sub][c4 * 4 + 3] = sw;
        ls[sub][128 + c4 * 4 + 0] = qx; ls[sub][128 + c4 * 4 + 1] = qy;
        ls[sub][128 + c4 * 4 + 2] = qz; ls[sub][128 + c4 * 4 + 3] = qw;
        __syncthreads();
        float t = 0.f;
#pragma unroll
        for (int k = 0; k < 8; ++k) t += ls[k][tid];
        atomicAdd(&stats16[(bb & 15) * 256 + tid], t);
    } else {
        // ---- degree histogram ----
        int e = (b - 1040) * 256 + tid;
        if (e < nE) atomicAdd(&deg[dst[e]], 1);
    }
}

// ---------------- phase2: normalize (nbNorm blks) + scanA -------------------
__global__ __launch_bounds__(256) void phase2_k(
    const float4* __restrict__ x, const float* __restrict__ stats16,
    const float4* __restrict__ gamma, const float4* __restrict__ beta,
    uint2* __restrict__ hbuf, int n, float inv_n, int nbNorm,
    const int* __restrict__ deg, int* __restrict__ bsum) {
    int b = blockIdx.x, tid = threadIdx.x;
    if (b < nbNorm) {
        // sum the 16 stat shards once per block through LDS
        __shared__ float fs[256];
        float a = 0.f;
#pragma unroll
        for (int sh = 0; sh < 16; ++sh) a += stats16[sh * 256 + tid];
        fs[tid] = a;
        __syncthreads();
        int c4 = tid & 31, sub = tid >> 5;
        int row = b * 8 + sub;
        float4 sm = ((const float4*)fs)[c4], sq = ((const float4*)fs)[32 + c4];
        float4 g = gamma[c4], bt = beta[c4];
        float mx = sm.x * inv_n, my = sm.y * inv_n, mz = sm.z * inv_n, mw = sm.w * inv_n;
        float vx = sq.x * inv_n - mx * mx, vy = sq.y * inv_n - my * my;
        float vz = sq.z * inv_n - mz * mz, vw = sq.w * inv_n - mw * mw;
        float scx = rsqrtf(vx + 1e-5f) * g.x, scy = rsqrtf(vy + 1e-5f) * g.y;
        float scz = rsqrtf(vz + 1e-5f) * g.z, scw = rsqrtf(vw + 1e-5f) * g.w;
        float shx = bt.x - mx * scx, shy = bt.y - my * scy;
        float shz = bt.z - mz * scz, shw = bt.w - mw * scw;
        if (row < n) {
            float4 v = x[(size_t)row * 32 + c4];
            float hx = v.x * scx + shx, hy = v.y * scy + shy;
            float hz = v.z * scz + shz, hw = v.w * scw + shw;
            uint2 o;
            o.x = (unsigned)f2bf(hx) | ((unsigned)f2bf(hy) << 16);
            o.y = (unsigned)f2bf(hz) | ((unsigned)f2bf(hw) << 16);
            hbuf[(size_t)row * 32 + c4] = o;
        }
    } else {
        // ---- scanA: per-block sum of 1024 degrees ----
        int bb = b - nbNorm;
        int i0 = bb * 1024 + tid * 4;
        int4 v = {0, 0, 0, 0};
        if (i0 + 3 < n) v = *(const int4*)(deg + i0);
        else {
            if (i0 < n) v.x = deg[i0];
            if (i0 + 1 < n) v.y = deg[i0 + 1];
            if (i0 + 2 < n) v.z = deg[i0 + 2];
        }
        __shared__ int ls[256];
        ls[tid] = v.x + v.y + v.z + v.w;
        __syncthreads();
#pragma unroll
        for (int off = 128; off > 0; off >>= 1) {
            if (tid < off) ls[tid] += ls[tid + off];
            __syncthreads();
        }
        if (tid == 0) bsum[bb] = ls[0];
    }
}

__global__ __launch_bounds__(256) void scanB_k(
    const int* __restrict__ bsum, int* __restrict__ bpref,
    int* __restrict__ offsets, int nb, int n) {
    __shared__ int ls[256];
    int t = threadIdx.x;
    ls[t] = (t < nb) ? bsum[t] : 0;
    __syncthreads();
#pragma unroll
    for (int off = 1; off < 256; off <<= 1) {
        int x = (t >= off) ? ls[t - off] : 0;
        __syncthreads();
        ls[t] += x;
        __syncthreads();
    }
    if (t < nb) bpref[t] = (t == 0) ? 0 : ls[t - 1];
    if (t == nb - 1) offsets[n] = ls[t];
}

__global__ __launch_bounds__(256) void scanC_k(
    const int* __restrict__ deg, const int* __restrict__ bpref,
    int* __restrict__ offsets, int* __restrict__ cursor, int n) {
    int b = blockIdx.x, t = threadIdx.x;
    int i0 = b * 1024 + t * 4;
    int4 v = {0, 0, 0, 0};
    if (i0 + 3 < n) v = *(const int4*)(deg + i0);
    else {
        if (i0 < n) v.x = deg[i0];
        if (i0 + 1 < n) v.y = deg[i0 + 1];
        if (i0 + 2 < n) v.z = deg[i0 + 2];
    }
    int s = v.x + v.y + v.z + v.w;
    __shared__ int ls[256];
    ls[t] = s;
    __syncthreads();
#pragma unroll
    for (int off = 1; off < 256; off <<= 1) {
        int x = (t >= off) ? ls[t - off] : 0;
        __syncthreads();
        ls[t] += x;
        __syncthreads();
    }
    int run = bpref[b] + ((t == 0) ? 0 : ls[t - 1]);
    int4 o;
    o.x = run; o.y = run + v.x; o.z = o.y + v.y; o.w = o.z + v.z;
    if (i0 + 3 < n) {
        *(int4*)(offsets + i0) = o;
        *(int4*)(cursor + i0) = o;
    } else {
        if (i0 < n) { offsets[i0] = o.x; cursor[i0] = o.x; }
        if (i0 + 1 < n) { offsets[i0 + 1] = o.y; cursor[i0 + 1] = o.y; }
        if (i0 + 2 < n) { offsets[i0 + 2] = o.z; cursor[i0 + 2] = o.z; }
    }
}

// ---------------- bin: src indices into CSR ----------------
__global__ __launch_bounds__(256) void bin_k(
    const int* __restrict__ src, const int* __restrict__ dst,
    int* __restrict__ cursor, int* __restrict__ csr, int nE) {
    int e = blockIdx.x * 256 + threadIdx.x;
    if (e < nE) {
        int p = atomicAdd(&cursor[dst[e]], 1);
        csr[p] = src[e];
    }
}

// ---------------- pull: per-node mean of h[src] -> bf16 hn_buf --------------
__global__ __launch_bounds__(256) void pull_k(
    const int* __restrict__ offsets, const int* __restrict__ csr,
    const unsigned* __restrict__ h32, unsigned* __restrict__ hnw, int n) {
    int wid = (blockIdx.x * 256 + threadIdx.x) >> 6;
    int lane = threadIdx.x & 63;
    if (wid >= n) return;
    int b0 = offsets[wid], b1 = offsets[wid + 1];
    float a0 = 0.f, a1 = 0.f;
    int j = b0;
    for (; j + 8 <= b1; j += 8) {
        unsigned u[8];
#pragma unroll
        for (int q = 0; q < 8; ++q) u[q] = h32[(size_t)csr[j + q] * 64 + lane];
#pragma unroll
        for (int q = 0; q < 8; ++q) {
            a0 += bf2f((unsigned short)(u[q] & 0xffff));
            a1 += bf2f((unsigned short)(u[q] >> 16));
        }
    }
    for (; j + 2 <= b1; j += 2) {
        unsigned u0 = h32[(size_t)csr[j] * 64 + lane];
        unsigned u1 = h32[(size_t)csr[j + 1] * 64 + lane];
        a0 += bf2f((unsigned short)(u0 & 0xffff)) + bf2f((unsigned short)(u1 & 0xffff));
        a1 += bf2f((unsigned short)(u0 >> 16)) + bf2f((unsigned short)(u1 >> 16));
    }
    if (j < b1) {
        unsigned u0 = h32[(size_t)csr[j] * 64 + lane];
        a0 += bf2f((unsigned short)(u0 & 0xffff));
        a1 += bf2f((unsigned short)(u0 >> 16));
    }
    float rd = (b1 > b0) ? 1.0f / (float)(b1 - b0) : 0.0f;
    unsigned o = (unsigned)f2bf(a0 * rd) | ((unsigned)f2bf(a1 * rd) << 16);
    hnw[(size_t)wid * 64 + lane] = o;
}

// ---------------- gemm: split-N blocks of 128 rows x 64 cols ----------------
// C = gelu_tanh( h@(Ws+I) + hn@Wn + b ); B-half (32 KB) in LDS.
__global__ __launch_bounds__(256, 4) void gemm_k(
    const unsigned short* __restrict__ h, const unsigned short* __restrict__ hn,
    const unsigned short* __restrict__ Bpre, const float* __restrict__ bias,
    float* __restrict__ out, int n) {
    __shared__ unsigned short Bsw[16384];  // 32 KB: this block's 64-col half
    int tid = threadIdx.x, wave = tid >> 6, lane = tid & 63;
    int H = blockIdx.x & 1, rb = blockIdx.x >> 1;
    // stage B-half: groups g=(s*4+tt), 1 KB each, via global_load_lds w16
#pragma unroll
    for (int i = 0; i < 8; ++i) {
        int g = wave * 8 + i;            // 0..31
        int s = g >> 2, tt = g & 3;
        __builtin_amdgcn_global_load_lds(
            (const __attribute__((address_space(1))) void*)(
                Bpre + ((size_t)((s * 8 + H * 4 + tt) * 64) + lane) * 8),
            (__attribute__((address_space(3))) void*)(Bsw + (size_t)g * 512),
            16, 0, 0);
    }
    __syncthreads();

    int quad = lane >> 4, mrow = lane & 15;
    int r0 = rb * 128 + wave * 32;
    int rA0 = min(r0 + mrow, n - 1);
    int rA1 = min(r0 + 16 + mrow, n - 1);

    f32x4 zero = {0.0f, 0.0f, 0.0f, 0.0f};
    f32x4 acc[2][4];
#pragma unroll
    for (int m = 0; m < 2; ++m)
#pragma unroll
        for (int t = 0; t < 4; ++t) acc[m][t] = zero;

#pragma unroll
    for (int s = 0; s < 8; ++s) {
        int kb = s * 32 + quad * 8;
        short8 a0, a1;
        if (s < 4) {
            a0 = *(const short8*)(h + (size_t)rA0 * 128 + kb);
            a1 = *(const short8*)(h + (size_t)rA1 * 128 + kb);
        } else {
            int kk = kb - 128;
            a0 = *(const short8*)(hn + (size_t)rA0 * 128 + kk);
            a1 = *(const short8*)(hn + (size_t)rA1 * 128 + kk);
        }
#pragma unroll
        for (int tt = 0; tt < 4; ++tt) {
            short8 b = *(const short8*)(Bsw + ((size_t)(s * 4 + tt) * 64 + lane) * 8);
            acc[0][tt] = __builtin_amdgcn_mfma_f32_16x16x32_bf16(a0, b, acc[0][tt], 0, 0, 0);
            acc[1][tt] = __builtin_amdgcn_mfma_f32_16x16x32_bf16(a1, b, acc[1][tt], 0, 0, 0);
        }
    }

    float bi[4];
#pragma unroll
    for (int t = 0; t < 4; ++t) bi[t] = bias[H * 64 + t * 16 + mrow];
#pragma unroll
    for (int m = 0; m < 2; ++m) {
#pragma unroll
        for (int i = 0; i < 4; ++i) {
            int row = r0 + m * 16 + quad * 4 + i;
            if (row < n) {
#pragma unroll
                for (int t = 0; t < 4; ++t) {
                    int col = H * 64 + t * 16 + mrow;
                    float xv = acc[m][t][i] + bi[t];
                    float x2 = xv * xv;
                    float u = 0.7978845608f * xv * (1.0f + 0.044715f * x2);
                    float e = __expf(2.0f * u);
                    float th = 1.0f - 2.0f * __builtin_amdgcn_rcpf(e + 1.0f);
                    out[(size_t)row * 128 + col] = 0.5f * xv * (1.0f + th);
                }
            }
        }
    }
}

extern "C" void kernel_launch(void* const* d_in, const int* in_sizes, int n_in,
                              void* d_out, int out_size, void* d_ws, size_t ws_size,
                              hipStream_t stream) {
    const float* features = (const float*)d_in[0];
    const int* src = (const int*)d_in[1];
    const int* dst = (const int*)d_in[2];
    const float* gamma = (const float*)d_in[3];
    const float* beta = (const float*)d_in[4];
    const float* Wself = (const float*)d_in[5];
    const float* Wneigh = (const float*)d_in[6];
    const float* bias = (const float*)d_in[7];
    int n = in_sizes[0] / DD;
    int nE = in_sizes[1];
    int nb = (n + 1023) / 1024;        // scan tiles (<=256)
    int nbHist = (nE + 255) / 256;
    int nbNorm = (n + 7) / 8;

    auto align1k = [](size_t x) { return (x + 1023) & ~(size_t)1023; };
    char* ws = (char*)d_ws;
    size_t off = 0;
    float* stats16 = (float*)(ws + off);     off += 16384;  // 16 shards x 256
    int* deg     = (int*)(ws + off);         off += align1k((size_t)n * 4);  // contig w/ stats
    int* offsets = (int*)(ws + off);         off += align1k((size_t)(n + 1) * 4);
    int* cursor  = (int*)(ws + off);         off += align1k((size_t)n * 4);
    int* csr     = (int*)(ws + off);         off += align1k((size_t)nE * 4);
    int* bsum    = (int*)(ws + off);         off += 1024;
    int* bpref   = (int*)(ws + off);         off += 1024;
    unsigned short* Bpre = (unsigned short*)(ws + off); off += 65536;
    unsigned short* hbuf = (unsigned short*)(ws + off); off += (size_t)n * 256;
    unsigned short* hnbuf = (unsigned short*)(ws + off); off += (size_t)n * 256;

    // stats16 (16 KB) and deg are contiguous: one memset covers both
    hipMemsetAsync(stats16, 0, 16384 + (size_t)n * 4, stream);

    phase1_k<<<16 + 1024 + nbHist, 256, 0, stream>>>(
        (const float4*)features, stats16, n, dst, deg, nE, Wself, Wneigh, Bpre);
    phase2_k<<<nbNorm + nb, 256, 0, stream>>>(
        (const float4*)features, stats16, (const float4*)gamma,
        (const float4*)beta, (uint2*)hbuf, n, 1.0f / (float)n, nbNorm,
        deg, bsum);
    scanB_k<<<1, 256, 0, stream>>>(bsum, bpref, offsets, nb, n);
    scanC_k<<<nb, 256, 0, stream>>>(deg, bpref, offsets, cursor, n);
    bin_k<<<nbHist, 256, 0, stream>>>(src, dst, cursor, csr, nE);
    pull_k<<<(n * 64 + 255) / 256, 256, 0, stream>>>(
        offsets, csr, (const unsigned*)hbuf, (unsigned*)hnbuf, n);
    gemm_k<<<((n + 127) / 128) * 2, 256, 0, stream>>>(
        hbuf, hnbuf, Bpre, bias, (float*)d_out, n);
}

// Round 7
// 226.291 us; speedup vs baseline: 7.0340x; 1.1873x over previous
//
#include <hip/hip_runtime.h>

#define DD 128
#define NPB_LOG 9
#define NPB 512      // nodes per bucket
#define EPB 1024     // edges per chunk

typedef __attribute__((ext_vector_type(8))) short short8;
typedef __attribute__((ext_vector_type(4))) float f32x4;

__device__ inline unsigned short f2bf(float f) {
    unsigned u = __float_as_uint(f);
    unsigned r = u + 0x7fffu + ((u >> 16) & 1u);
    return (unsigned short)(r >> 16);
}
__device__ inline float bf2f(unsigned short s) {
    return __uint_as_float(((unsigned)s) << 16);
}

// ---- phase1: prep(16) + bn_stats(1024, sharded atomics) + sortA(histogram) --
__global__ __launch_bounds__(256) void phase1_k(
    const float4* __restrict__ x, float* __restrict__ stats16, int n,
    const int* __restrict__ dst, int nE, int NCHUNK, int NBUCK,
    const float* __restrict__ Wself, const float* __restrict__ Wneigh,
    unsigned short* __restrict__ Bpre, int* __restrict__ cm) {
    int b = blockIdx.x, tid = threadIdx.x;
    __shared__ float ls[8][256];  // 8 KB, aliased as int in sortA branch
    if (b < 16) {
        // ---- prep: swizzle [Wself+I; Wneigh] -> bf16 MFMA fragment order ----
        int q = b * 256 + tid;  // 0..4095
        int l = q & 63;
        int kb = ((q >> 9) << 5) + ((l >> 4) << 3);
        int nn = (((q >> 6) & 7) << 4) + (l & 15);
        bool self = (kb < 128);
        const float* Wp = self ? (Wself + (size_t)kb * 128 + nn)
                               : (Wneigh + (size_t)(kb - 128) * 128 + nn);
        unsigned tmp[4];
#pragma unroll
        for (int j = 0; j < 4; ++j) {
            float v0 = Wp[(2 * j) * 128];
            float v1 = Wp[(2 * j + 1) * 128];
            if (self) {  // fold skip connection: W_self + I
                if (kb + 2 * j == nn) v0 += 1.0f;
                if (kb + 2 * j + 1 == nn) v1 += 1.0f;
            }
            tmp[j] = (unsigned)f2bf(v0) | ((unsigned)f2bf(v1) << 16);
        }
        uint4 w; w.x = tmp[0]; w.y = tmp[1]; w.z = tmp[2]; w.w = tmp[3];
        *(uint4*)(Bpre + (size_t)q * 8) = w;
    } else if (b < 16 + 1024) {
        // ---- BN stats: sum & sumsq per feature, atomics sharded x16 ----
        int bb = b - 16;
        int c4 = tid & 31, sub = tid >> 5;
        float sx = 0.f, sy = 0.f, sz = 0.f, sw = 0.f;
        float qx = 0.f, qy = 0.f, qz = 0.f, qw = 0.f;
        for (int r = bb * 8 + sub; r < n; r += 1024 * 8) {
            float4 v = x[(size_t)r * 32 + c4];
            sx += v.x; sy += v.y; sz += v.z; sw += v.w;
            qx += v.x * v.x; qy += v.y * v.y; qz += v.z * v.z; qw += v.w * v.w;
        }
        ls[sub][c4 * 4 + 0] = sx; ls[sub][c4 * 4 + 1] = sy;
        ls[sub][c4 * 4 + 2] = sz; ls[sub][c4 * 4 + 3] = sw;
        ls[sub][128 + c4 * 4 + 0] = qx; ls[sub][128 + c4 * 4 + 1] = qy;
        ls[sub][128 + c4 * 4 + 2] = qz; ls[sub][128 + c4 * 4 + 3] = qw;
        __syncthreads();
        float t = 0.f;
#pragma unroll
        for (int k = 0; k < 8; ++k) t += ls[k][tid];
        atomicAdd(&stats16[(bb & 15) * 256 + tid], t);
    } else {
        // ---- sortA: LDS histogram of this chunk's edges by dst bucket ----
        int chunk = b - 1040;
        int* cnt = (int*)ls;
        for (int i = tid; i < NPB; i += 256) cnt[i] = 0;
        __syncthreads();
        int e0 = chunk * EPB;
#pragma unroll
        for (int j = 0; j < 4; ++j) {
            int e = e0 + j * 256 + tid;
            if (e < nE) atomicAdd(&cnt[dst[e] >> NPB_LOG], 1);
        }
        __syncthreads();
        for (int bk = tid; bk < NBUCK; bk += 256)
            cm[(size_t)bk * NCHUNK + chunk] = cnt[bk];
    }
}

// ---- generic hierarchical scan (also used for the count matrix) ------------
__global__ __launch_bounds__(256) void scanA_k(
    const int* __restrict__ v_in, int* __restrict__ bsum, int n) {
    int b = blockIdx.x, t = threadIdx.x;
    int i0 = b * 1024 + t * 4;
    int4 v = {0, 0, 0, 0};
    if (i0 + 3 < n) v = *(const int4*)(v_in + i0);
    else {
        if (i0 < n) v.x = v_in[i0];
        if (i0 + 1 < n) v.y = v_in[i0 + 1];
        if (i0 + 2 < n) v.z = v_in[i0 + 2];
    }
    __shared__ int ls[256];
    ls[t] = v.x + v.y + v.z + v.w;
    __syncthreads();
#pragma unroll
    for (int off = 128; off > 0; off >>= 1) {
        if (t < off) ls[t] += ls[t + off];
        __syncthreads();
    }
    if (t == 0) bsum[b] = ls[0];
}

__global__ __launch_bounds__(256) void scanB_k(
    const int* __restrict__ bsum, int* __restrict__ bpref,
    int* __restrict__ total_out, int nb, int n) {
    __shared__ int ls[256];
    int t = threadIdx.x;
    ls[t] = (t < nb) ? bsum[t] : 0;
    __syncthreads();
#pragma unroll
    for (int off = 1; off < 256; off <<= 1) {
        int x = (t >= off) ? ls[t - off] : 0;
        __syncthreads();
        ls[t] += x;
        __syncthreads();
    }
    if (t < nb) bpref[t] = (t == 0) ? 0 : ls[t - 1];
    if (t == nb - 1) total_out[n] = ls[t];
}

__global__ __launch_bounds__(256) void scanC_k(
    const int* __restrict__ v_in, const int* __restrict__ bpref,
    int* __restrict__ o1, int* __restrict__ o2, int n) {
    int b = blockIdx.x, t = threadIdx.x;
    int i0 = b * 1024 + t * 4;
    int4 v = {0, 0, 0, 0};
    if (i0 + 3 < n) v = *(const int4*)(v_in + i0);
    else {
        if (i0 < n) v.x = v_in[i0];
        if (i0 + 1 < n) v.y = v_in[i0 + 1];
        if (i0 + 2 < n) v.z = v_in[i0 + 2];
    }
    int s = v.x + v.y + v.z + v.w;
    __shared__ int ls[256];
    ls[t] = s;
    __syncthreads();
#pragma unroll
    for (int off = 1; off < 256; off <<= 1) {
        int x = (t >= off) ? ls[t - off] : 0;
        __syncthreads();
        ls[t] += x;
        __syncthreads();
    }
    int run = bpref[b] + ((t == 0) ? 0 : ls[t - 1]);
    int4 o;
    o.x = run; o.y = run + v.x; o.z = o.y + v.y; o.w = o.z + v.z;
    if (i0 + 3 < n) {
        *(int4*)(o1 + i0) = o;
        *(int4*)(o2 + i0) = o;
    } else {
        if (i0 < n) { o1[i0] = o.x; o2[i0] = o.x; }
        if (i0 + 1 < n) { o1[i0 + 1] = o.y; o2[i0 + 1] = o.y; }
        if (i0 + 2 < n) { o1[i0 + 2] = o.z; o2[i0 + 2] = o.z; }
    }
}

// ---- phase2: normalize(nbNorm) + sortB (scatter edges to bucket groups) ----
__global__ __launch_bounds__(256) void phase2_k(
    const float4* __restrict__ x, const float* __restrict__ stats16,
    const float4* __restrict__ gamma, const float4* __restrict__ beta,
    uint2* __restrict__ hbuf, int n, float inv_n, int nbNorm,
    const int* __restrict__ src, const int* __restrict__ dst,
    const int* __restrict__ cmscan, unsigned* __restrict__ pairs,
    int nE, int NCHUNK, int NBUCK) {
    int b = blockIdx.x, tid = threadIdx.x;
    __shared__ int shr[512];
    if (b < nbNorm) {
        float* fs = (float*)shr;
        float a = 0.f;
#pragma unroll
        for (int sh = 0; sh < 16; ++sh) a += stats16[sh * 256 + tid];
        fs[tid] = a;
        __syncthreads();
        int c4 = tid & 31, sub = tid >> 5;
        int row = b * 8 + sub;
        float4 sm = ((const float4*)fs)[c4], sq = ((const float4*)fs)[32 + c4];
        float4 g = gamma[c4], bt = beta[c4];
        float mx = sm.x * inv_n, my = sm.y * inv_n, mz = sm.z * inv_n, mw = sm.w * inv_n;
        float vx = sq.x * inv_n - mx * mx, vy = sq.y * inv_n - my * my;
        float vz = sq.z * inv_n - mz * mz, vw = sq.w * inv_n - mw * mw;
        float scx = rsqrtf(vx + 1e-5f) * g.x, scy = rsqrtf(vy + 1e-5f) * g.y;
        float scz = rsqrtf(vz + 1e-5f) * g.z, scw = rsqrtf(vw + 1e-5f) * g.w;
        float shx = bt.x - mx * scx, shy = bt.y - my * scy;
        float shz = bt.z - mz * scz, shw = bt.w - mw * scw;
        if (row < n) {
            float4 v = x[(size_t)row * 32 + c4];
            float hx = v.x * scx + shx, hy = v.y * scy + shy;
            float hz = v.z * scz + shz, hw = v.w * scw + shw;
            uint2 o;
            o.x = (unsigned)f2bf(hx) | ((unsigned)f2bf(hy) << 16);
            o.y = (unsigned)f2bf(hz) | ((unsigned)f2bf(hw) << 16);
            hbuf[(size_t)row * 32 + c4] = o;
        }
    } else {
        // ---- sortB: place each edge into its dst-bucket group -------------
        int chunk = b - nbNorm;
        for (int i = tid; i < NBUCK; i += 256)
            shr[i] = cmscan[(size_t)i * NCHUNK + chunk];
        __syncthreads();
        int e0 = chunk * EPB;
#pragma unroll
        for (int j = 0; j < 4; ++j) {
            int e = e0 + j * 256 + tid;
            if (e < nE) {
                int d = dst[e];
                int p = atomicAdd(&shr[d >> NPB_LOG], 1);
                pairs[p] = ((unsigned)src[e] << NPB_LOG) | (unsigned)(d & (NPB - 1));
            }
        }
    }
}

// ---- sortC: per-bucket fine counting sort -> offsets + csr (LDS only) ------
__global__ __launch_bounds__(256) void sortC_k(
    const unsigned* __restrict__ pairs, const int* __restrict__ cmscan,
    int* __restrict__ offsets, int* __restrict__ csr,
    int n, int nE, int NCHUNK, int NBUCK) {
    int b = blockIdx.x, tid = threadIdx.x;
    int base0 = cmscan[(size_t)b * NCHUNK];
    int end = (b + 1 < NBUCK) ? cmscan[(size_t)(b + 1) * NCHUNK] : nE;
    __shared__ int cnt[NPB];
    __shared__ int cur[NPB];
    __shared__ int ps[256];
    for (int i = tid; i < NPB; i += 256) cnt[i] = 0;
    __syncthreads();
    for (int e = base0 + tid; e < end; e += 256)
        atomicAdd(&cnt[pairs[e] & (NPB - 1)], 1);
    __syncthreads();
    int c0 = cnt[2 * tid], c1 = cnt[2 * tid + 1];
    ps[tid] = c0 + c1;
    __syncthreads();
#pragma unroll
    for (int off = 1; off < 256; off <<= 1) {
        int v = (tid >= off) ? ps[tid - off] : 0;
        __syncthreads();
        ps[tid] += v;
        __syncthreads();
    }
    int ex = base0 + ((tid == 0) ? 0 : ps[tid - 1]);
    cur[2 * tid] = ex;
    cur[2 * tid + 1] = ex + c0;
    int node0 = b * NPB + 2 * tid;
    if (node0 < n) offsets[node0] = ex;
    if (node0 + 1 < n) offsets[node0 + 1] = ex + c0;
    if (b == NBUCK - 1 && tid == 0) offsets[n] = nE;
    __syncthreads();
    for (int e = base0 + tid; e < end; e += 256) {
        unsigned u = pairs[e];
        int p = atomicAdd(&cur[u & (NPB - 1)], 1);
        csr[p] = (int)(u >> NPB_LOG);
    }
}

// ---- pull: per-node mean of h[src] -> bf16 hn_buf --------------------------
__global__ __launch_bounds__(256) void pull_k(
    const int* __restrict__ offsets, const int* __restrict__ csr,
    const unsigned* __restrict__ h32, unsigned* __restrict__ hnw, int n) {
    int wid = (blockIdx.x * 256 + threadIdx.x) >> 6;
    int lane = threadIdx.x & 63;
    if (wid >= n) return;
    int b0 = offsets[wid], b1 = offsets[wid + 1];
    float a0 = 0.f, a1 = 0.f;
    int j = b0;
    for (; j + 8 <= b1; j += 8) {
        unsigned u[8];
#pragma unroll
        for (int q = 0; q < 8; ++q) u[q] = h32[(size_t)csr[j + q] * 64 + lane];
#pragma unroll
        for (int q = 0; q < 8; ++q) {
            a0 += bf2f((unsigned short)(u[q] & 0xffff));
            a1 += bf2f((unsigned short)(u[q] >> 16));
        }
    }
    for (; j + 2 <= b1; j += 2) {
        unsigned u0 = h32[(size_t)csr[j] * 64 + lane];
        unsigned u1 = h32[(size_t)csr[j + 1] * 64 + lane];
        a0 += bf2f((unsigned short)(u0 & 0xffff)) + bf2f((unsigned short)(u1 & 0xffff));
        a1 += bf2f((unsigned short)(u0 >> 16)) + bf2f((unsigned short)(u1 >> 16));
    }
    if (j < b1) {
        unsigned u0 = h32[(size_t)csr[j] * 64 + lane];
        a0 += bf2f((unsigned short)(u0 & 0xffff));
        a1 += bf2f((unsigned short)(u0 >> 16));
    }
    float rd = (b1 > b0) ? 1.0f / (float)(b1 - b0) : 0.0f;
    unsigned o = (unsigned)f2bf(a0 * rd) | ((unsigned)f2bf(a1 * rd) << 16);
    hnw[(size_t)wid * 64 + lane] = o;
}

// ---- gemm: split-N blocks of 128 rows x 64 cols ----------------------------
__global__ __launch_bounds__(256, 4) void gemm_k(
    const unsigned short* __restrict__ h, const unsigned short* __restrict__ hn,
    const unsigned short* __restrict__ Bpre, const float* __restrict__ bias,
    float* __restrict__ out, int n) {
    __shared__ unsigned short Bsw[16384];  // 32 KB: this block's 64-col half
    int tid = threadIdx.x, wave = tid >> 6, lane = tid & 63;
    int H = blockIdx.x & 1, rb = blockIdx.x >> 1;
#pragma unroll
    for (int i = 0; i < 8; ++i) {
        int g = wave * 8 + i;            // 0..31
        int s = g >> 2, tt = g & 3;
        __builtin_amdgcn_global_load_lds(
            (const __attribute__((address_space(1))) void*)(
                Bpre + ((size_t)((s * 8 + H * 4 + tt) * 64) + lane) * 8),
            (__attribute__((address_space(3))) void*)(Bsw + (size_t)g * 512),
            16, 0, 0);
    }
    __syncthreads();

    int quad = lane >> 4, mrow = lane & 15;
    int r0 = rb * 128 + wave * 32;
    int rA0 = min(r0 + mrow, n - 1);
    int rA1 = min(r0 + 16 + mrow, n - 1);

    f32x4 zero = {0.0f, 0.0f, 0.0f, 0.0f};
    f32x4 acc[2][4];
#pragma unroll
    for (int m = 0; m < 2; ++m)
#pragma unroll
        for (int t = 0; t < 4; ++t) acc[m][t] = zero;

#pragma unroll
    for (int s = 0; s < 8; ++s) {
        int kb = s * 32 + quad * 8;
        short8 a0, a1;
        if (s < 4) {
            a0 = *(const short8*)(h + (size_t)rA0 * 128 + kb);
            a1 = *(const short8*)(h + (size_t)rA1 * 128 + kb);
        } else {
            int kk = kb - 128;
            a0 = *(const short8*)(hn + (size_t)rA0 * 128 + kk);
            a1 = *(const short8*)(hn + (size_t)rA1 * 128 + kk);
        }
#pragma unroll
        for (int tt = 0; tt < 4; ++tt) {
            short8 b = *(const short8*)(Bsw + ((size_t)(s * 4 + tt) * 64 + lane) * 8);
            acc[0][tt] = __builtin_amdgcn_mfma_f32_16x16x32_bf16(a0, b, acc[0][tt], 0, 0, 0);
            acc[1][tt] = __builtin_amdgcn_mfma_f32_16x16x32_bf16(a1, b, acc[1][tt], 0, 0, 0);
        }
    }

    float bi[4];
#pragma unroll
    for (int t = 0; t < 4; ++t) bi[t] = bias[H * 64 + t * 16 + mrow];
#pragma unroll
    for (int m = 0; m < 2; ++m) {
#pragma unroll
        for (int i = 0; i < 4; ++i) {
            int row = r0 + m * 16 + quad * 4 + i;
            if (row < n) {
#pragma unroll
                for (int t = 0; t < 4; ++t) {
                    int col = H * 64 + t * 16 + mrow;
                    float xv = acc[m][t][i] + bi[t];
                    float x2 = xv * xv;
                    float u = 0.7978845608f * xv * (1.0f + 0.044715f * x2);
                    float e = __expf(2.0f * u);
                    float th = 1.0f - 2.0f * __builtin_amdgcn_rcpf(e + 1.0f);
                    out[(size_t)row * 128 + col] = 0.5f * xv * (1.0f + th);
                }
            }
        }
    }
}

extern "C" void kernel_launch(void* const* d_in, const int* in_sizes, int n_in,
                              void* d_out, int out_size, void* d_ws, size_t ws_size,
                              hipStream_t stream) {
    const float* features = (const float*)d_in[0];
    const int* src = (const int*)d_in[1];
    const int* dst = (const int*)d_in[2];
    const float* gamma = (const float*)d_in[3];
    const float* beta = (const float*)d_in[4];
    const float* Wself = (const float*)d_in[5];
    const float* Wneigh = (const float*)d_in[6];
    const float* bias = (const float*)d_in[7];
    int n = in_sizes[0] / DD;
    int nE = in_sizes[1];
    int NCHUNK = (nE + EPB - 1) / EPB;          // 782
    int NBUCK = (n + NPB - 1) / NPB;            // 196
    int CM = NBUCK * NCHUNK;                    // 152,672
    int tilesCM = (CM + 1023) / 1024;           // 150 (<=256 for scanB)
    int nbNorm = (n + 7) / 8;

    auto align1k = [](size_t x) { return (x + 1023) & ~(size_t)1023; };
    char* ws = (char*)d_ws;
    size_t off = 0;
    float* stats16 = (float*)(ws + off);       off += 16384;
    int* cm       = (int*)(ws + off);          off += align1k((size_t)(CM + 1) * 4);
    int* cmscan   = (int*)(ws + off);          off += align1k((size_t)CM * 4);
    int* offsets  = (int*)(ws + off);          off += align1k((size_t)(n + 1) * 4);
    int* csr      = (int*)(ws + off);          off += align1k((size_t)nE * 4);
    unsigned* pairs = (unsigned*)(ws + off);   off += align1k((size_t)nE * 4);
    int* bsum     = (int*)(ws + off);          off += 1024;
    int* bpref    = (int*)(ws + off);          off += 1024;
    unsigned short* Bpre = (unsigned short*)(ws + off); off += 65536;
    unsigned short* hbuf = (unsigned short*)(ws + off); off += (size_t)n * 256;
    unsigned short* hnbuf = (unsigned short*)(ws + off); off += (size_t)n * 256;

    hipMemsetAsync(stats16, 0, 16384, stream);

    phase1_k<<<16 + 1024 + NCHUNK, 256, 0, stream>>>(
        (const float4*)features, stats16, n, dst, nE, NCHUNK, NBUCK,
        Wself, Wneigh, Bpre, cm);
    scanA_k<<<tilesCM, 256, 0, stream>>>(cm, bsum, CM);
    scanB_k<<<1, 256, 0, stream>>>(bsum, bpref, cm, tilesCM, CM);
    scanC_k<<<tilesCM, 256, 0, stream>>>(cm, bpref, cmscan, cmscan, CM);
    phase2_k<<<nbNorm + NCHUNK, 256, 0, stream>>>(
        (const float4*)features, stats16, (const float4*)gamma,
        (const float4*)beta, (uint2*)hbuf, n, 1.0f / (float)n, nbNorm,
        src, dst, cmscan, pairs, nE, NCHUNK, NBUCK);
    sortC_k<<<NBUCK, 256, 0, stream>>>(pairs, cmscan, offsets, csr, n, nE,
                                       NCHUNK, NBUCK);
    pull_k<<<(n * 64 + 255) / 256, 256, 0, stream>>>(
        offsets, csr, (const unsigned*)hbuf, (unsigned*)hnbuf, n);
    gemm_k<<<((n + 127) / 128) * 2, 256, 0, stream>>>(
        hbuf, hnbuf, Bpre, bias, (float*)d_out, n);
}

// Round 8
// 225.187 us; speedup vs baseline: 7.0685x; 1.0049x over previous
//
#include <hip/hip_runtime.h>

#define DD 128
#define NPB_LOG 8
#define NPB 256      // nodes per bucket
#define EPB 2048     // edges per chunk

typedef __attribute__((ext_vector_type(8))) short short8;
typedef __attribute__((ext_vector_type(4))) float f32x4;
typedef __attribute__((ext_vector_type(2))) float f32x2;

__device__ inline unsigned short f2bf(float f) {
    unsigned u = __float_as_uint(f);
    unsigned r = u + 0x7fffu + ((u >> 16) & 1u);
    return (unsigned short)(r >> 16);
}
__device__ inline float bf2f(unsigned short s) {
    return __uint_as_float(((unsigned)s) << 16);
}

// ---- phase1: prep(16) + bn_stats(1024, sharded atomics) + sortA(histogram) --
__global__ __launch_bounds__(256) void phase1_k(
    const float4* __restrict__ x, float* __restrict__ stats16, int n,
    const int* __restrict__ dst, int nE, int NCHUNK, int NBUCK,
    const float* __restrict__ Wself, const float* __restrict__ Wneigh,
    unsigned short* __restrict__ Bpre, int* __restrict__ cm) {
    int b = blockIdx.x, tid = threadIdx.x;
    __shared__ float ls[8][256];  // 8 KB, aliased as int in sortA branch
    if (b < 16) {
        // ---- prep: swizzle [Wself+I; Wneigh] -> bf16 MFMA fragment order ----
        int q = b * 256 + tid;  // 0..4095
        int l = q & 63;
        int kb = ((q >> 9) << 5) + ((l >> 4) << 3);
        int nn = (((q >> 6) & 7) << 4) + (l & 15);
        bool self = (kb < 128);
        const float* Wp = self ? (Wself + (size_t)kb * 128 + nn)
                               : (Wneigh + (size_t)(kb - 128) * 128 + nn);
        unsigned tmp[4];
#pragma unroll
        for (int j = 0; j < 4; ++j) {
            float v0 = Wp[(2 * j) * 128];
            float v1 = Wp[(2 * j + 1) * 128];
            if (self) {  // fold skip connection: W_self + I
                if (kb + 2 * j == nn) v0 += 1.0f;
                if (kb + 2 * j + 1 == nn) v1 += 1.0f;
            }
            tmp[j] = (unsigned)f2bf(v0) | ((unsigned)f2bf(v1) << 16);
        }
        uint4 w; w.x = tmp[0]; w.y = tmp[1]; w.z = tmp[2]; w.w = tmp[3];
        *(uint4*)(Bpre + (size_t)q * 8) = w;
    } else if (b < 16 + 1024) {
        // ---- BN stats: sum & sumsq per feature, atomics sharded x16 ----
        int bb = b - 16;
        int c4 = tid & 31, sub = tid >> 5;
        float sx = 0.f, sy = 0.f, sz = 0.f, sw = 0.f;
        float qx = 0.f, qy = 0.f, qz = 0.f, qw = 0.f;
        for (int r = bb * 8 + sub; r < n; r += 1024 * 8) {
            float4 v = x[(size_t)r * 32 + c4];
            sx += v.x; sy += v.y; sz += v.z; sw += v.w;
            qx += v.x * v.x; qy += v.y * v.y; qz += v.z * v.z; qw += v.w * v.w;
        }
        ls[sub][c4 * 4 + 0] = sx; ls[sub][c4 * 4 + 1] = sy;
        ls[sub][c4 * 4 + 2] = sz; ls[sub][c4 * 4 + 3] = sw;
        ls[sub][128 + c4 * 4 + 0] = qx; ls[sub][128 + c4 * 4 + 1] = qy;
        ls[sub][128 + c4 * 4 + 2] = qz; ls[sub][128 + c4 * 4 + 3] = qw;
        __syncthreads();
        float t = 0.f;
#pragma unroll
        for (int k = 0; k < 8; ++k) t += ls[k][tid];
        atomicAdd(&stats16[(bb & 15) * 256 + tid], t);
    } else {
        // ---- sortA: LDS histogram of this chunk's edges by dst bucket ----
        int chunk = b - 1040;
        int* cnt = (int*)ls;
        for (int i = tid; i < NBUCK; i += 256) cnt[i] = 0;
        __syncthreads();
        int e0 = chunk * EPB;
#pragma unroll
        for (int j = 0; j < 8; ++j) {
            int e = e0 + j * 256 + tid;
            if (e < nE) atomicAdd(&cnt[dst[e] >> NPB_LOG], 1);
        }
        __syncthreads();
        for (int bk = tid; bk < NBUCK; bk += 256)
            cm[(size_t)bk * NCHUNK + chunk] = cnt[bk];
    }
}

// ---- generic hierarchical scan (over the count matrix) ---------------------
__global__ __launch_bounds__(256) void scanA_k(
    const int* __restrict__ v_in, int* __restrict__ bsum, int n) {
    int b = blockIdx.x, t = threadIdx.x;
    int i0 = b * 1024 + t * 4;
    int4 v = {0, 0, 0, 0};
    if (i0 + 3 < n) v = *(const int4*)(v_in + i0);
    else {
        if (i0 < n) v.x = v_in[i0];
        if (i0 + 1 < n) v.y = v_in[i0 + 1];
        if (i0 + 2 < n) v.z = v_in[i0 + 2];
    }
    __shared__ int ls[256];
    ls[t] = v.x + v.y + v.z + v.w;
    __syncthreads();
#pragma unroll
    for (int off = 128; off > 0; off >>= 1) {
        if (t < off) ls[t] += ls[t + off];
        __syncthreads();
    }
    if (t == 0) bsum[b] = ls[0];
}

__global__ __launch_bounds__(256) void scanB_k(
    const int* __restrict__ bsum, int* __restrict__ bpref,
    int* __restrict__ total_out, int nb, int n) {
    __shared__ int ls[256];
    int t = threadIdx.x;
    ls[t] = (t < nb) ? bsum[t] : 0;
    __syncthreads();
#pragma unroll
    for (int off = 1; off < 256; off <<= 1) {
        int x = (t >= off) ? ls[t - off] : 0;
        __syncthreads();
        ls[t] += x;
        __syncthreads();
    }
    if (t < nb) bpref[t] = (t == 0) ? 0 : ls[t - 1];
    if (t == nb - 1) total_out[n] = ls[t];
}

__global__ __launch_bounds__(256) void scanC_k(
    const int* __restrict__ v_in, const int* __restrict__ bpref,
    int* __restrict__ o1, int* __restrict__ o2, int n) {
    int b = blockIdx.x, t = threadIdx.x;
    int i0 = b * 1024 + t * 4;
    int4 v = {0, 0, 0, 0};
    if (i0 + 3 < n) v = *(const int4*)(v_in + i0);
    else {
        if (i0 < n) v.x = v_in[i0];
        if (i0 + 1 < n) v.y = v_in[i0 + 1];
        if (i0 + 2 < n) v.z = v_in[i0 + 2];
    }
    int s = v.x + v.y + v.z + v.w;
    __shared__ int ls[256];
    ls[t] = s;
    __syncthreads();
#pragma unroll
    for (int off = 1; off < 256; off <<= 1) {
        int x = (t >= off) ? ls[t - off] : 0;
        __syncthreads();
        ls[t] += x;
        __syncthreads();
    }
    int run = bpref[b] + ((t == 0) ? 0 : ls[t - 1]);
    int4 o;
    o.x = run; o.y = run + v.x; o.z = o.y + v.y; o.w = o.z + v.z;
    if (i0 + 3 < n) {
        *(int4*)(o1 + i0) = o;
        *(int4*)(o2 + i0) = o;
    } else {
        if (i0 < n) { o1[i0] = o.x; o2[i0] = o.x; }
        if (i0 + 1 < n) { o1[i0 + 1] = o.y; o2[i0 + 1] = o.y; }
        if (i0 + 2 < n) { o1[i0 + 2] = o.z; o2[i0 + 2] = o.z; }
    }
}

// ---- phase2: normalize (writes bf16 h AND fp8 h8) + sortB ------------------
__global__ __launch_bounds__(256) void phase2_k(
    const float4* __restrict__ x, const float* __restrict__ stats16,
    const float4* __restrict__ gamma, const float4* __restrict__ beta,
    uint2* __restrict__ hbuf, unsigned* __restrict__ h8, int n, float inv_n,
    int nbNorm, const int* __restrict__ src, const int* __restrict__ dst,
    const int* __restrict__ cmscan, unsigned* __restrict__ pairs,
    int nE, int NCHUNK, int NBUCK) {
    int b = blockIdx.x, tid = threadIdx.x;
    __shared__ int shr[512];
    if (b < nbNorm) {
        float* fs = (float*)shr;
        float a = 0.f;
#pragma unroll
        for (int sh = 0; sh < 16; ++sh) a += stats16[sh * 256 + tid];
        fs[tid] = a;
        __syncthreads();
        int c4 = tid & 31, sub = tid >> 5;
        int row = b * 8 + sub;
        float4 sm = ((const float4*)fs)[c4], sq = ((const float4*)fs)[32 + c4];
        float4 g = gamma[c4], bt = beta[c4];
        float mx = sm.x * inv_n, my = sm.y * inv_n, mz = sm.z * inv_n, mw = sm.w * inv_n;
        float vx = sq.x * inv_n - mx * mx, vy = sq.y * inv_n - my * my;
        float vz = sq.z * inv_n - mz * mz, vw = sq.w * inv_n - mw * mw;
        float scx = rsqrtf(vx + 1e-5f) * g.x, scy = rsqrtf(vy + 1e-5f) * g.y;
        float scz = rsqrtf(vz + 1e-5f) * g.z, scw = rsqrtf(vw + 1e-5f) * g.w;
        float shx = bt.x - mx * scx, shy = bt.y - my * scy;
        float shz = bt.z - mz * scz, shw = bt.w - mw * scw;
        if (row < n) {
            float4 v = x[(size_t)row * 32 + c4];
            float hx = v.x * scx + shx, hy = v.y * scy + shy;
            float hz = v.z * scz + shz, hw = v.w * scw + shw;
            uint2 o;
            o.x = (unsigned)f2bf(hx) | ((unsigned)f2bf(hy) << 16);
            o.y = (unsigned)f2bf(hz) | ((unsigned)f2bf(hw) << 16);
            hbuf[(size_t)row * 32 + c4] = o;
            int p8 = __builtin_amdgcn_cvt_pk_fp8_f32(hx, hy, 0, false);
            p8 = __builtin_amdgcn_cvt_pk_fp8_f32(hz, hw, p8, true);
            h8[(size_t)row * 32 + c4] = (unsigned)p8;
        }
    } else {
        // ---- sortB: place each edge into its dst-bucket group -------------
        int chunk = b - nbNorm;
        for (int i = tid; i < NBUCK; i += 256)
            shr[i] = cmscan[(size_t)i * NCHUNK + chunk];
        __syncthreads();
        int e0 = chunk * EPB;
#pragma unroll
        for (int j = 0; j < 8; ++j) {
            int e = e0 + j * 256 + tid;
            if (e < nE) {
                int d = dst[e];
                int p = atomicAdd(&shr[d >> NPB_LOG], 1);
                pairs[p] = ((unsigned)src[e] << NPB_LOG) | (unsigned)(d & (NPB - 1));
            }
        }
    }
}

// ---- sortC: per-bucket fine counting sort -> offsets + csr (LDS only) ------
__global__ __launch_bounds__(256) void sortC_k(
    const unsigned* __restrict__ pairs, const int* __restrict__ cmscan,
    int* __restrict__ offsets, int* __restrict__ csr,
    int n, int nE, int NCHUNK, int NBUCK) {
    int b = blockIdx.x, tid = threadIdx.x;
    int base0 = cmscan[(size_t)b * NCHUNK];
    int end = (b + 1 < NBUCK) ? cmscan[(size_t)(b + 1) * NCHUNK] : nE;
    __shared__ int cnt[NPB];
    __shared__ int cur[NPB];
    cnt[tid] = 0;
    __syncthreads();
    for (int e = base0 + tid; e < end; e += 256)
        atomicAdd(&cnt[pairs[e] & (NPB - 1)], 1);
    __syncthreads();
    int c0 = cnt[tid];
    __shared__ int ps[256];
    ps[tid] = c0;
    __syncthreads();
#pragma unroll
    for (int off = 1; off < 256; off <<= 1) {
        int v = (tid >= off) ? ps[tid - off] : 0;
        __syncthreads();
        ps[tid] += v;
        __syncthreads();
    }
    int ex = base0 + ps[tid] - c0;  // exclusive
    cur[tid] = ex;
    int node = b * NPB + tid;
    if (node < n) offsets[node] = ex;
    if (b == NBUCK - 1 && tid == 0) offsets[n] = nE;
    __syncthreads();
    for (int e = base0 + tid; e < end; e += 256) {
        unsigned u = pairs[e];
        int p = atomicAdd(&cur[u & (NPB - 1)], 1);
        csr[p] = (int)(u >> NPB_LOG);
    }
}

// ---- pull: per-node mean over fp8 h8 gather -> bf16 hn ---------------------
__global__ __launch_bounds__(256) void pull_k(
    const int* __restrict__ offsets, const int* __restrict__ csr,
    const unsigned short* __restrict__ h8u, unsigned* __restrict__ hnw, int n) {
    int wid = (blockIdx.x * 256 + threadIdx.x) >> 6;
    int lane = threadIdx.x & 63;
    if (wid >= n) return;
    int b0 = offsets[wid], b1 = offsets[wid + 1];
    float a0 = 0.f, a1 = 0.f;
    int j = b0;
    for (; j + 8 <= b1; j += 8) {
        unsigned short u[8];
#pragma unroll
        for (int q = 0; q < 8; ++q) u[q] = h8u[(size_t)csr[j + q] * 64 + lane];
#pragma unroll
        for (int q = 0; q < 8; ++q) {
            f32x2 fv = __builtin_amdgcn_cvt_pk_f32_fp8((unsigned)u[q], false);
            a0 += fv.x; a1 += fv.y;
        }
    }
    for (; j + 2 <= b1; j += 2) {
        unsigned short u0 = h8u[(size_t)csr[j] * 64 + lane];
        unsigned short u1 = h8u[(size_t)csr[j + 1] * 64 + lane];
        f32x2 f0 = __builtin_amdgcn_cvt_pk_f32_fp8((unsigned)u0, false);
        f32x2 f1 = __builtin_amdgcn_cvt_pk_f32_fp8((unsigned)u1, false);
        a0 += f0.x + f1.x; a1 += f0.y + f1.y;
    }
    if (j < b1) {
        unsigned short u0 = h8u[(size_t)csr[j] * 64 + lane];
        f32x2 f0 = __builtin_amdgcn_cvt_pk_f32_fp8((unsigned)u0, false);
        a0 += f0.x; a1 += f0.y;
    }
    float rd = (b1 > b0) ? 1.0f / (float)(b1 - b0) : 0.0f;
    unsigned o = (unsigned)f2bf(a0 * rd) | ((unsigned)f2bf(a1 * rd) << 16);
    hnw[(size_t)wid * 64 + lane] = o;
}

// ---- gemm: split-N blocks of 128 rows x 64 cols ----------------------------
__global__ __launch_bounds__(256, 4) void gemm_k(
    const unsigned short* __restrict__ h, const unsigned short* __restrict__ hn,
    const unsigned short* __restrict__ Bpre, const float* __restrict__ bias,
    float* __restrict__ out, int n) {
    __shared__ unsigned short Bsw[16384];  // 32 KB: this block's 64-col half
    int tid = threadIdx.x, wave = tid >> 6, lane = tid & 63;
    int H = blockIdx.x & 1, rb = blockIdx.x >> 1;
#pragma unroll
    for (int i = 0; i < 8; ++i) {
        int g = wave * 8 + i;            // 0..31
        int s = g >> 2, tt = g & 3;
        __builtin_amdgcn_global_load_lds(
            (const __attribute__((address_space(1))) void*)(
                Bpre + ((size_t)((s * 8 + H * 4 + tt) * 64) + lane) * 8),
            (__attribute__((address_space(3))) void*)(Bsw + (size_t)g * 512),
            16, 0, 0);
    }
    __syncthreads();

    int quad = lane >> 4, mrow = lane & 15;
    int r0 = rb * 128 + wave * 32;
    int rA0 = min(r0 + mrow, n - 1);
    int rA1 = min(r0 + 16 + mrow, n - 1);

    f32x4 zero = {0.0f, 0.0f, 0.0f, 0.0f};
    f32x4 acc[2][4];
#pragma unroll
    for (int m = 0; m < 2; ++m)
#pragma unroll
        for (int t = 0; t < 4; ++t) acc[m][t] = zero;

#pragma unroll
    for (int s = 0; s < 8; ++s) {
        int kb = s * 32 + quad * 8;
        short8 a0, a1;
        if (s < 4) {
            a0 = *(const short8*)(h + (size_t)rA0 * 128 + kb);
            a1 = *(const short8*)(h + (size_t)rA1 * 128 + kb);
        } else {
            int kk = kb - 128;
            a0 = *(const short8*)(hn + (size_t)rA0 * 128 + kk);
            a1 = *(const short8*)(hn + (size_t)rA1 * 128 + kk);
        }
#pragma unroll
        for (int tt = 0; tt < 4; ++tt) {
            short8 b = *(const short8*)(Bsw + ((size_t)(s * 4 + tt) * 64 + lane) * 8);
            acc[0][tt] = __builtin_amdgcn_mfma_f32_16x16x32_bf16(a0, b, acc[0][tt], 0, 0, 0);
            acc[1][tt] = __builtin_amdgcn_mfma_f32_16x16x32_bf16(a1, b, acc[1][tt], 0, 0, 0);
        }
    }

    float bi[4];
#pragma unroll
    for (int t = 0; t < 4; ++t) bi[t] = bias[H * 64 + t * 16 + mrow];
#pragma unroll
    for (int m = 0; m < 2; ++m) {
#pragma unroll
        for (int i = 0; i < 4; ++i) {
            int row = r0 + m * 16 + quad * 4 + i;
            if (row < n) {
#pragma unroll
                for (int t = 0; t < 4; ++t) {
                    int col = H * 64 + t * 16 + mrow;
                    float xv = acc[m][t][i] + bi[t];
                    float x2 = xv * xv;
                    float u = 0.7978845608f * xv * (1.0f + 0.044715f * x2);
                    float e = __expf(2.0f * u);
                    float th = 1.0f - 2.0f * __builtin_amdgcn_rcpf(e + 1.0f);
                    out[(size_t)row * 128 + col] = 0.5f * xv * (1.0f + th);
                }
            }
        }
    }
}

extern "C" void kernel_launch(void* const* d_in, const int* in_sizes, int n_in,
                              void* d_out, int out_size, void* d_ws, size_t ws_size,
                              hipStream_t stream) {
    const float* features = (const float*)d_in[0];
    const int* src = (const int*)d_in[1];
    const int* dst = (const int*)d_in[2];
    const float* gamma = (const float*)d_in[3];
    const float* beta = (const float*)d_in[4];
    const float* Wself = (const float*)d_in[5];
    const float* Wneigh = (const float*)d_in[6];
    const float* bias = (const float*)d_in[7];
    int n = in_sizes[0] / DD;
    int nE = in_sizes[1];
    int NCHUNK = (nE + EPB - 1) / EPB;          // 391
    int NBUCK = (n + NPB - 1) / NPB;            // 391
    int CM = NBUCK * NCHUNK;                    // 152,881
    int tilesCM = (CM + 1023) / 1024;           // 150 (<=256 for scanB)
    int nbNorm = (n + 7) / 8;

    auto align1k = [](size_t x) { return (x + 1023) & ~(size_t)1023; };
    char* ws = (char*)d_ws;
    size_t off = 0;
    float* stats16 = (float*)(ws + off);       off += 16384;
    int* cm       = (int*)(ws + off);          off += align1k((size_t)(CM + 1) * 4);
    int* cmscan   = (int*)(ws + off);          off += align1k((size_t)CM * 4);
    int* offsets  = (int*)(ws + off);          off += align1k((size_t)(n + 1) * 4);
    int* csr      = (int*)(ws + off);          off += align1k((size_t)nE * 4);
    unsigned* pairs = (unsigned*)(ws + off);   off += align1k((size_t)nE * 4);
    int* bsum     = (int*)(ws + off);          off += 1024;
    int* bpref    = (int*)(ws + off);          off += 1024;
    unsigned short* Bpre = (unsigned short*)(ws + off); off += 65536;
    unsigned short* hbuf = (unsigned short*)(ws + off); off += (size_t)n * 256;
    unsigned short* hnbuf = (unsigned short*)(ws + off); off += (size_t)n * 256;
    unsigned* h8 = (unsigned*)(ws + off);      off += (size_t)n * 128;

    hipMemsetAsync(stats16, 0, 16384, stream);

    phase1_k<<<16 + 1024 + NCHUNK, 256, 0, stream>>>(
        (const float4*)features, stats16, n, dst, nE, NCHUNK, NBUCK,
        Wself, Wneigh, Bpre, cm);
    scanA_k<<<tilesCM, 256, 0, stream>>>(cm, bsum, CM);
    scanB_k<<<1, 256, 0, stream>>>(bsum, bpref, cm, tilesCM, CM);
    scanC_k<<<tilesCM, 256, 0, stream>>>(cm, bpref, cmscan, cmscan, CM);
    phase2_k<<<nbNorm + NCHUNK, 256, 0, stream>>>(
        (const float4*)features, stats16, (const float4*)gamma,
        (const float4*)beta, (uint2*)hbuf, h8, n, 1.0f / (float)n, nbNorm,
        src, dst, cmscan, pairs, nE, NCHUNK, NBUCK);
    sortC_k<<<NBUCK, 256, 0, stream>>>(pairs, cmscan, offsets, csr, n, nE,
                                       NCHUNK, NBUCK);
    pull_k<<<(n * 64 + 255) / 256, 256, 0, stream>>>(
        offsets, csr, (const unsigned short*)h8, (unsigned*)hnbuf, n);
    gemm_k<<<((n + 127) / 128) * 2, 256, 0, stream>>>(
        hbuf, hnbuf, Bpre, bias, (float*)d_out, n);
}